// Round 4
// baseline (499.757 us; speedup 1.0000x reference)
//
#include <hip/hip_runtime.h>
#include <math.h>

#define NN 50000
#define NE 800000
#define HC 128
#define NHEAD 4
#define EMB 64
#define STATS_BLOCKS 64

__device__ __forceinline__ float lrelu(float x) { return x > 0.0f ? x : 0.2f * x; }
__device__ __forceinline__ float gelu_f(float x) {
    return 0.5f * x * (1.0f + erff(x * 0.70710678118654752440f));
}
__device__ __forceinline__ float sel4(float4 v, int h) {
    float r = v.x;
    r = (h == 1) ? v.y : r;
    r = (h == 2) ? v.z : r;
    r = (h == 3) ? v.w : r;
    return r;
}

// ---------------- fused frontend stats + degree histogram ----------------
__global__ void stats_hist_kernel(const float* __restrict__ rq, float* __restrict__ stats,
                                  const int* __restrict__ dst, int* __restrict__ deg) {
    if (blockIdx.x < STATS_BLOCKS) {
        int i = blockIdx.x * 256 + threadIdx.x;
        float s = 0.f, s2 = 0.f;
        for (; i < NN; i += STATS_BLOCKS * 256) {
            float v = rq[i];
            s += v; s2 += v * v;
        }
        #pragma unroll
        for (int off = 32; off > 0; off >>= 1) {
            s  += __shfl_down(s, off);
            s2 += __shfl_down(s2, off);
        }
        __shared__ float ls[4], ls2[4];
        int lane = threadIdx.x & 63, wid = threadIdx.x >> 6;
        if (lane == 0) { ls[wid] = s; ls2[wid] = s2; }
        __syncthreads();
        if (threadIdx.x == 0) {
            float a = ls[0] + ls[1] + ls[2] + ls[3];
            float b = ls2[0] + ls2[1] + ls2[2] + ls2[3];
            atomicAdd(&stats[0], a);
            atomicAdd(&stats[1], b);
        }
    } else {
        int i = (blockIdx.x - STATS_BLOCKS) * 256 + threadIdx.x;
        if (i < NE) atomicAdd(&deg[dst[i]], 1);
    }
}

// ---------------- CSR build ----------------
__global__ void scan1_kernel(const int* __restrict__ deg, int* __restrict__ row_excl,
                             int* __restrict__ bsum) {
    __shared__ int tmp[256];
    int t = threadIdx.x;
    int i = blockIdx.x * 256 + t;
    int v = (i < NN) ? deg[i] : 0;
    tmp[t] = v;
    __syncthreads();
    #pragma unroll
    for (int off = 1; off < 256; off <<= 1) {
        int add = (t >= off) ? tmp[t - off] : 0;
        __syncthreads();
        tmp[t] += add;
        __syncthreads();
    }
    if (i < NN) row_excl[i] = tmp[t] - v;
    if (t == 255) bsum[blockIdx.x] = tmp[255];
}

__global__ void scan2_kernel(int* __restrict__ bsum, int nb) {
    __shared__ int tmp[256];
    int t = threadIdx.x;
    int v = (t < nb) ? bsum[t] : 0;
    tmp[t] = v;
    __syncthreads();
    #pragma unroll
    for (int off = 1; off < 256; off <<= 1) {
        int add = (t >= off) ? tmp[t - off] : 0;
        __syncthreads();
        tmp[t] += add;
        __syncthreads();
    }
    if (t < nb) bsum[t] = tmp[t] - v;  // exclusive block offsets
}

__global__ void scan3_kernel(int* __restrict__ row_excl, const int* __restrict__ bsum) {
    int i = blockIdx.x * blockDim.x + threadIdx.x;
    if (i < NN) row_excl[i] += bsum[i >> 8];
    if (i == 0) row_excl[NN] = NE;
}

// fills segments back-to-front via atomicSub on deg (deg ends at 0; not reused)
__global__ void scatter_kernel(const int* __restrict__ src, const int* __restrict__ dst,
                               const int* __restrict__ row_start, int* __restrict__ deg,
                               int* __restrict__ src_sorted) {
    int i = blockIdx.x * blockDim.x + threadIdx.x;
    if (i < NE) {
        int d = dst[i];
        int pos = row_start[d] + atomicSub(&deg[d], 1) - 1;
        src_sorted[pos] = src[i];
    }
}

// ---- fused GEMM + attention projections: h = x@W ; als/ald per-head dots ----
// 128 thr; tile 64 rows x 128 cols; micro 8x8 (cols tc*4..+3 and 64+tc*4..+3).
// L0=1: builds x rows on the fly from emb[label], normalized rq (no x buffer read).
template <int L0>
__launch_bounds__(128)
__global__ void gemm_al_kernel(const float* __restrict__ x, const float* __restrict__ W,
                               const float* __restrict__ a_src, const float* __restrict__ a_dst,
                               float* __restrict__ h, float* __restrict__ als,
                               float* __restrict__ ald,
                               const int* __restrict__ label, const float* __restrict__ rq,
                               const float* __restrict__ emb, const float* __restrict__ reqW,
                               const float* __restrict__ reqb, const float* __restrict__ stats) {
    __shared__ float sW[16][128];    // 8 KB
    __shared__ float sX[16][68];     // 4.25 KB, pad 68 -> 2-way max on all accesses
    int t = threadIdx.x;
    int row0 = blockIdx.x * 64;
    int tr = t >> 4;   // 0..7 -> rows tr*8..+7
    int tc = t & 15;   // col groups tc*4 and 64+tc*4

    float mean = 0.f, inv = 0.f;
    if (L0) {
        float sum = stats[0], sumsq = stats[1];
        mean = sum / (float)NN;
        float var = (sumsq - sum * sum / (float)NN) / (float)(NN - 1);
        inv = 1.0f / (sqrtf(var) + 1e-6f);
    }

    float acc[8][8] = {};
    for (int kk = 0; kk < 128; kk += 16) {
        if (kk) __syncthreads();
        #pragma unroll
        for (int i = 0; i < 4; i++)
            ((float4*)sW)[t + 128 * i] = ((const float4*)(W + kk * 128))[t + 128 * i];
        #pragma unroll
        for (int i = 0; i < 2; i++) {
            int ii = t + 128 * i;        // 0..255
            int r = ii >> 2;             // 0..63
            int q = ii & 3;              // float4 slot within 16-k chunk
            int rr = row0 + r;
            float4 v = make_float4(0.f, 0.f, 0.f, 0.f);
            if (rr < NN) {
                if (L0) {
                    if (kk < 64) {
                        v = ((const float4*)(emb + (size_t)label[rr] * EMB))[(kk >> 2) + q];
                    } else {
                        int j4 = ((kk - 64) >> 2) + q;
                        float4 w = ((const float4*)reqW)[j4];
                        float4 b = ((const float4*)reqb)[j4];
                        float rr2 = (rq[rr] - mean) * inv;
                        v = make_float4(rr2 * w.x + b.x, rr2 * w.y + b.y,
                                        rr2 * w.z + b.z, rr2 * w.w + b.w);
                    }
                } else {
                    v = *(const float4*)(x + (size_t)rr * 128 + kk + q * 4);
                }
            }
            sX[q * 4 + 0][r] = v.x;
            sX[q * 4 + 1][r] = v.y;
            sX[q * 4 + 2][r] = v.z;
            sX[q * 4 + 3][r] = v.w;
        }
        __syncthreads();
        #pragma unroll
        for (int k = 0; k < 16; k++) {
            float4 xv0 = *(const float4*)(&sX[k][tr * 8]);
            float4 xv1 = *(const float4*)(&sX[k][tr * 8 + 4]);
            float4 wv0 = *(const float4*)(&sW[k][tc * 4]);
            float4 wv1 = *(const float4*)(&sW[k][64 + tc * 4]);
            float xr[8] = {xv0.x, xv0.y, xv0.z, xv0.w, xv1.x, xv1.y, xv1.z, xv1.w};
            #pragma unroll
            for (int j = 0; j < 8; j++) {
                acc[j][0] += xr[j] * wv0.x;
                acc[j][1] += xr[j] * wv0.y;
                acc[j][2] += xr[j] * wv0.z;
                acc[j][3] += xr[j] * wv0.w;
                acc[j][4] += xr[j] * wv1.x;
                acc[j][5] += xr[j] * wv1.y;
                acc[j][6] += xr[j] * wv1.z;
                acc[j][7] += xr[j] * wv1.w;
            }
        }
    }

    // epilogue: h store + fused attention projections
    float4 as0 = *(const float4*)(a_src + tc * 4);
    float4 as1 = *(const float4*)(a_src + 64 + tc * 4);
    float4 ad0 = *(const float4*)(a_dst + tc * 4);
    float4 ad1 = *(const float4*)(a_dst + 64 + tc * 4);
    int headA = tc >> 3;          // cols [0,64): heads 0/1
    int headB = 2 + (tc >> 3);    // cols [64,128): heads 2/3
    #pragma unroll
    for (int j = 0; j < 8; j++) {
        int rr = row0 + tr * 8 + j;
        float psa = acc[j][0] * as0.x + acc[j][1] * as0.y + acc[j][2] * as0.z + acc[j][3] * as0.w;
        float psb = acc[j][4] * as1.x + acc[j][5] * as1.y + acc[j][6] * as1.z + acc[j][7] * as1.w;
        float pda = acc[j][0] * ad0.x + acc[j][1] * ad0.y + acc[j][2] * ad0.z + acc[j][3] * ad0.w;
        float pdb = acc[j][4] * ad1.x + acc[j][5] * ad1.y + acc[j][6] * ad1.z + acc[j][7] * ad1.w;
        psa += __shfl_xor(psa, 1); psb += __shfl_xor(psb, 1);
        pda += __shfl_xor(pda, 1); pdb += __shfl_xor(pdb, 1);
        psa += __shfl_xor(psa, 2); psb += __shfl_xor(psb, 2);
        pda += __shfl_xor(pda, 2); pdb += __shfl_xor(pdb, 2);
        psa += __shfl_xor(psa, 4); psb += __shfl_xor(psb, 4);
        pda += __shfl_xor(pda, 4); pdb += __shfl_xor(pdb, 4);
        if (rr < NN) {
            *(float4*)(&h[(size_t)rr * 128 + tc * 4]) =
                make_float4(acc[j][0], acc[j][1], acc[j][2], acc[j][3]);
            *(float4*)(&h[(size_t)rr * 128 + 64 + tc * 4]) =
                make_float4(acc[j][4], acc[j][5], acc[j][6], acc[j][7]);
            if ((tc & 7) == 0) {
                als[rr * 4 + headA] = psa;
                als[rr * 4 + headB] = psb;
                ald[rr * 4 + headA] = pda;
                ald[rr * 4 + headB] = pdb;
            }
        }
    }
}

// ---------------- per-node softmax aggregation ----------------
// one wave/node; lane = (sub 0..3 edge slot, cg 0..15 channel group of 8)
// inner loop: 16 edges/iter (4/lane) -> 8 b128 gathers in flight per lane
__launch_bounds__(256)
__global__ void agg_kernel(const float* __restrict__ h, const float* __restrict__ als_,
                           const float* __restrict__ ald_, const int* __restrict__ row_start,
                           const int* __restrict__ src_sorted, const float* __restrict__ bias,
                           float* __restrict__ out) {
    __shared__ float lds_p[4][4][68];   // [wave][head][edge]; 68: (4h+e) distinct mod 32
    __shared__ int   lds_s[4][64];
    int wid = threadIdx.x >> 6;
    int lane = threadIdx.x & 63;
    int node = blockIdx.x * 4 + wid;
    if (node >= NN) return;
    int sub  = lane >> 4;    // edge slot
    int cg   = lane & 15;    // channel group
    int c0   = cg * 8;
    int head = cg >> 2;

    int start = row_start[node], end = row_start[node + 1];
    float4 adv = *(const float4*)(ald_ + (size_t)node * 4);
    float4 avs = *(const float4*)(als_ + (size_t)node * 4);

    // self-loop (sub==0 only; sub-reduced at the end)
    float p_self = __expf(lrelu(sel4(avs, head) + sel4(adv, head)));
    float pinit = (sub == 0) ? p_self : 0.f;
    float s_sum = pinit;
    const float* hn = h + (size_t)node * 128 + c0;
    float4 hs0 = *(const float4*)hn;
    float4 hs1 = *(const float4*)(hn + 4);
    float acc[8] = {hs0.x * pinit, hs0.y * pinit, hs0.z * pinit, hs0.w * pinit,
                    hs1.x * pinit, hs1.y * pinit, hs1.z * pinit, hs1.w * pinit};

    for (int base = start; base < end; base += 64) {
        int j = base + lane;
        int my = 0;
        float4 p4 = make_float4(0.f, 0.f, 0.f, 0.f);
        if (j < end) {
            my = src_sorted[j];
            float4 av = *(const float4*)(als_ + (size_t)my * 4);
            p4.x = __expf(lrelu(av.x + adv.x));
            p4.y = __expf(lrelu(av.y + adv.y));
            p4.z = __expf(lrelu(av.z + adv.z));
            p4.w = __expf(lrelu(av.w + adv.w));
        }
        lds_s[wid][lane] = my;
        lds_p[wid][0][lane] = p4.x;
        lds_p[wid][1][lane] = p4.y;
        lds_p[wid][2][lane] = p4.z;
        lds_p[wid][3][lane] = p4.w;
        __builtin_amdgcn_wave_barrier();

        int cnt = end - base;
        if (cnt > 64) cnt = 64;
        for (int jj = 0; jj < cnt; jj += 16) {
            int   s[4];
            float p[4];
            #pragma unroll
            for (int i = 0; i < 4; i++) {
                int e = jj + 4 * i + sub;
                bool v = e < cnt;
                int ec = v ? e : 0;
                s[i] = lds_s[wid][ec];
                float pv = lds_p[wid][head][ec];
                p[i] = v ? pv : 0.f;
            }
            float4 A[4], B[4];
            #pragma unroll
            for (int i = 0; i < 4; i++) {
                const float* hp = h + (size_t)s[i] * 128 + c0;
                A[i] = *(const float4*)hp;
                B[i] = *(const float4*)(hp + 4);
            }
            #pragma unroll
            for (int i = 0; i < 4; i++) {
                s_sum += p[i];
                acc[0] += A[i].x * p[i]; acc[1] += A[i].y * p[i];
                acc[2] += A[i].z * p[i]; acc[3] += A[i].w * p[i];
                acc[4] += B[i].x * p[i]; acc[5] += B[i].y * p[i];
                acc[6] += B[i].z * p[i]; acc[7] += B[i].w * p[i];
            }
        }
        __builtin_amdgcn_wave_barrier();
    }

    // reduce partial sums across the 4 edge slots (lane bits 4,5)
    #pragma unroll
    for (int i = 0; i < 8; i++) {
        acc[i] += __shfl_xor(acc[i], 16);
        acc[i] += __shfl_xor(acc[i], 32);
    }
    s_sum += __shfl_xor(s_sum, 16);
    s_sum += __shfl_xor(s_sum, 32);

    float invs = 1.0f / (s_sum + 1e-16f);
    // each lane outputs channels c0 + 2*sub, c0 + 2*sub + 1 (parallel gelu)
    float t0 = (sub & 1) ? acc[2] : acc[0];
    float t1 = (sub & 1) ? acc[6] : acc[4];
    float num0 = (sub & 2) ? t1 : t0;
    float u0 = (sub & 1) ? acc[3] : acc[1];
    float u1 = (sub & 1) ? acc[7] : acc[5];
    float num1 = (sub & 2) ? u1 : u0;
    int cc = c0 + 2 * sub;
    float2 bv = *(const float2*)(bias + cc);
    float o0 = gelu_f(num0 * invs + bv.x);
    float o1 = gelu_f(num1 * invs + bv.y);
    *(float2*)(out + (size_t)node * 128 + cc) = make_float2(o0, o1);
}

extern "C" void kernel_launch(void* const* d_in, const int* in_sizes, int n_in,
                              void* d_out, int out_size, void* d_ws, size_t ws_size,
                              hipStream_t stream) {
    const int*   label = (const int*)d_in[0];
    const int*   eidx  = (const int*)d_in[1];          // [2, NE]
    const float* rq    = (const float*)d_in[3];
    const float* emb   = (const float*)d_in[4];
    const float* reqW  = (const float*)d_in[5];
    const float* reqb  = (const float*)d_in[6];
    const float* W[3]    = {(const float*)d_in[7],  (const float*)d_in[11], (const float*)d_in[15]};
    const float* asrc[3] = {(const float*)d_in[8],  (const float*)d_in[12], (const float*)d_in[16]};
    const float* adst[3] = {(const float*)d_in[9],  (const float*)d_in[13], (const float*)d_in[17]};
    const float* bias[3] = {(const float*)d_in[10], (const float*)d_in[14], (const float*)d_in[18]};

    const int* e_src = eidx;
    const int* e_dst = eidx + NE;

    char* ws = (char*)d_ws;
    size_t off = 0;
    auto A = [&](size_t n) { size_t o = off; off += (n + 255) & ~(size_t)255; return o; };
    size_t o_deg   = A((size_t)NN * 4);        // zeroed
    size_t o_stats = A(8);                     // zeroed
    size_t zero_bytes = off;
    size_t o_row   = A((size_t)(NN + 1) * 4);
    size_t o_bsum  = A(256 * 4);
    size_t o_srcS  = A((size_t)NE * 4);
    size_t o_x     = A((size_t)NN * 128 * 4);
    size_t o_h     = A((size_t)NN * 128 * 4);
    size_t o_als   = A((size_t)NN * 4 * 4);
    size_t o_ald   = A((size_t)NN * 4 * 4);
    (void)ws_size; (void)n_in; (void)in_sizes; (void)out_size;

    int*   deg    = (int*)(ws + o_deg);
    float* stats  = (float*)(ws + o_stats);
    int*   rowst  = (int*)(ws + o_row);
    int*   bsum   = (int*)(ws + o_bsum);
    int*   srcS   = (int*)(ws + o_srcS);
    float* x      = (float*)(ws + o_x);
    float* h      = (float*)(ws + o_h);
    float* als    = (float*)(ws + o_als);
    float* ald    = (float*)(ws + o_ald);

    hipMemsetAsync(ws, 0, zero_bytes, stream);

    // fused frontend stats + degree histogram
    stats_hist_kernel<<<STATS_BLOCKS + (NE + 255) / 256, 256, 0, stream>>>(rq, stats, e_dst, deg);

    // CSR build (self-loops handled analytically in agg)
    const int nb_scan = (NN + 255) / 256;  // 196
    scan1_kernel<<<nb_scan, 256, 0, stream>>>(deg, rowst, bsum);
    scan2_kernel<<<1, 256, 0, stream>>>(bsum, nb_scan);
    scan3_kernel<<<nb_scan, 256, 0, stream>>>(rowst, bsum);
    scatter_kernel<<<(NE + 255) / 256, 256, 0, stream>>>(e_src, e_dst, rowst, deg, srcS);

    // 3 GAT layers
    const int gemm_blocks = (NN + 63) / 64;        // 782
    const int agg_blocks = (NN + 3) / 4;           // 12500
    for (int l = 0; l < 3; l++) {
        if (l == 0)
            gemm_al_kernel<1><<<gemm_blocks, 128, 0, stream>>>(x, W[l], asrc[l], adst[l], h, als, ald,
                                                               label, rq, emb, reqW, reqb, stats);
        else
            gemm_al_kernel<0><<<gemm_blocks, 128, 0, stream>>>(x, W[l], asrc[l], adst[l], h, als, ald,
                                                               label, rq, emb, reqW, reqb, stats);
        float* dst_buf = (l == 2) ? (float*)d_out : x;
        agg_kernel<<<agg_blocks, 256, 0, stream>>>(h, als, ald, rowst, srcS, bias[l], dst_buf);
    }
}

// Round 6
// 378.909 us; speedup vs baseline: 1.3189x; 1.3189x over previous
//
#include <hip/hip_runtime.h>
#include <hip/hip_fp16.h>
#include <math.h>

#define NN 50000
#define NE 800000
#define HC 128
#define NHEAD 4
#define EMB 64
#define STATS_BLOCKS 64

__device__ __forceinline__ float lrelu(float x) { return x > 0.0f ? x : 0.2f * x; }
__device__ __forceinline__ float gelu_f(float x) {
    return 0.5f * x * (1.0f + erff(x * 0.70710678118654752440f));
}
__device__ __forceinline__ float sel4(float4 v, int h) {
    float r = v.x;
    r = (h == 1) ? v.y : r;
    r = (h == 2) ? v.z : r;
    r = (h == 3) ? v.w : r;
    return r;
}
// pack 4 fp32 -> 4 fp16 (RNE) in 8 bytes
__device__ __forceinline__ float2 pack4h(float a, float b, float c, float d) {
    __half2 lo = __floats2half2_rn(a, b);
    __half2 hi = __floats2half2_rn(c, d);
    float2 r;
    ((__half2*)&r)[0] = lo;
    ((__half2*)&r)[1] = hi;
    return r;
}

// ---------------- fused frontend stats + degree histogram ----------------
__global__ void stats_hist_kernel(const float* __restrict__ rq, float* __restrict__ stats,
                                  const int* __restrict__ dst, int* __restrict__ deg) {
    if (blockIdx.x < STATS_BLOCKS) {
        int i = blockIdx.x * 256 + threadIdx.x;
        float s = 0.f, s2 = 0.f;
        for (; i < NN; i += STATS_BLOCKS * 256) {
            float v = rq[i];
            s += v; s2 += v * v;
        }
        #pragma unroll
        for (int off = 32; off > 0; off >>= 1) {
            s  += __shfl_down(s, off);
            s2 += __shfl_down(s2, off);
        }
        __shared__ float ls[4], ls2[4];
        int lane = threadIdx.x & 63, wid = threadIdx.x >> 6;
        if (lane == 0) { ls[wid] = s; ls2[wid] = s2; }
        __syncthreads();
        if (threadIdx.x == 0) {
            atomicAdd(&stats[0], ls[0] + ls[1] + ls[2] + ls[3]);
            atomicAdd(&stats[1], ls2[0] + ls2[1] + ls2[2] + ls2[3]);
        }
    } else {
        int i = (blockIdx.x - STATS_BLOCKS) * 256 + threadIdx.x;
        if (i < NE) atomicAdd(&deg[dst[i]], 1);
    }
}

// ---------------- CSR build ----------------
__global__ void scan1_kernel(const int* __restrict__ deg, int* __restrict__ row_excl,
                             int* __restrict__ bsum) {
    __shared__ int tmp[256];
    int t = threadIdx.x;
    int i = blockIdx.x * 256 + t;
    int v = (i < NN) ? deg[i] : 0;
    tmp[t] = v;
    __syncthreads();
    #pragma unroll
    for (int off = 1; off < 256; off <<= 1) {
        int add = (t >= off) ? tmp[t - off] : 0;
        __syncthreads();
        tmp[t] += add;
        __syncthreads();
    }
    if (i < NN) row_excl[i] = tmp[t] - v;
    if (t == 255) bsum[blockIdx.x] = tmp[255];
}

__global__ void scan2_kernel(int* __restrict__ bsum, int nb) {
    __shared__ int tmp[256];
    int t = threadIdx.x;
    int v = (t < nb) ? bsum[t] : 0;
    tmp[t] = v;
    __syncthreads();
    #pragma unroll
    for (int off = 1; off < 256; off <<= 1) {
        int add = (t >= off) ? tmp[t - off] : 0;
        __syncthreads();
        tmp[t] += add;
        __syncthreads();
    }
    if (t < nb) bsum[t] = tmp[t] - v;  // exclusive block offsets
}

__global__ void scan3_kernel(int* __restrict__ row_excl, const int* __restrict__ bsum) {
    int i = blockIdx.x * blockDim.x + threadIdx.x;
    if (i < NN) row_excl[i] += bsum[i >> 8];
    if (i == 0) row_excl[NN] = NE;
}

// fills segments back-to-front via atomicSub on deg (deg ends at 0; not reused)
__global__ void scatter_kernel(const int* __restrict__ src, const int* __restrict__ dst,
                               const int* __restrict__ row_start, int* __restrict__ deg,
                               int* __restrict__ src_sorted) {
    int i = blockIdx.x * blockDim.x + threadIdx.x;
    if (i < NE) {
        int d = dst[i];
        int pos = row_start[d] + atomicSub(&deg[d], 1) - 1;
        src_sorted[pos] = src[i];
    }
}

// ---- fused GEMM + attention projections: h(fp16) = x@W ; als/ald per-head fp32 ----
// 256 thr; tile 64 rows x 128 cols; micro 4x8 (cols tc*4 and 64+tc*4); BK=32.
// L0=1: builds x rows on the fly from emb[label], normalized rq.
template <int L0>
__launch_bounds__(256)
__global__ void gemm_al_kernel(const float* __restrict__ x, const float* __restrict__ W,
                               const float* __restrict__ a_src, const float* __restrict__ a_dst,
                               __half* __restrict__ h, float* __restrict__ als,
                               float* __restrict__ ald,
                               const int* __restrict__ label, const float* __restrict__ rq,
                               const float* __restrict__ emb, const float* __restrict__ reqW,
                               const float* __restrict__ reqb, const float* __restrict__ stats) {
    __shared__ float sW[32][128];    // 16 KB
    __shared__ float sX[32][68];     // 8.7 KB
    int t = threadIdx.x;
    int row0 = blockIdx.x * 64;
    int tr = t >> 4;   // 0..15 -> rows tr*4..+3
    int tc = t & 15;   // col groups tc*4 and 64+tc*4

    float mean = 0.f, inv = 0.f;
    if (L0) {
        float sum = stats[0], sumsq = stats[1];
        mean = sum / (float)NN;
        float var = (sumsq - sum * sum / (float)NN) / (float)(NN - 1);
        inv = 1.0f / (sqrtf(var) + 1e-6f);
    }

    float acc[4][8] = {};
    for (int kk = 0; kk < 128; kk += 32) {
        if (kk) __syncthreads();
        #pragma unroll
        for (int i = 0; i < 4; i++)
            ((float4*)sW)[t + 256 * i] = ((const float4*)(W + kk * 128))[t + 256 * i];
        #pragma unroll
        for (int i = 0; i < 2; i++) {
            int ii = t + 256 * i;        // 0..511
            int r = ii >> 3;             // 0..63
            int q = ii & 7;              // float4 slot within 32-k chunk
            int rr = row0 + r;
            float4 v = make_float4(0.f, 0.f, 0.f, 0.f);
            if (rr < NN) {
                if (L0) {
                    if (kk < 64) {
                        v = ((const float4*)(emb + (size_t)label[rr] * EMB))[(kk >> 2) + q];
                    } else {
                        int j4 = ((kk - 64) >> 2) + q;
                        float4 w = ((const float4*)reqW)[j4];
                        float4 b = ((const float4*)reqb)[j4];
                        float rr2 = (rq[rr] - mean) * inv;
                        v = make_float4(rr2 * w.x + b.x, rr2 * w.y + b.y,
                                        rr2 * w.z + b.z, rr2 * w.w + b.w);
                    }
                } else {
                    v = *(const float4*)(x + (size_t)rr * 128 + kk + q * 4);
                }
            }
            sX[q * 4 + 0][r] = v.x;
            sX[q * 4 + 1][r] = v.y;
            sX[q * 4 + 2][r] = v.z;
            sX[q * 4 + 3][r] = v.w;
        }
        __syncthreads();
        #pragma unroll
        for (int k = 0; k < 32; k++) {
            float4 xv  = *(const float4*)(&sX[k][tr * 4]);
            float4 wv0 = *(const float4*)(&sW[k][tc * 4]);
            float4 wv1 = *(const float4*)(&sW[k][64 + tc * 4]);
            float xr[4] = {xv.x, xv.y, xv.z, xv.w};
            #pragma unroll
            for (int j = 0; j < 4; j++) {
                acc[j][0] += xr[j] * wv0.x;
                acc[j][1] += xr[j] * wv0.y;
                acc[j][2] += xr[j] * wv0.z;
                acc[j][3] += xr[j] * wv0.w;
                acc[j][4] += xr[j] * wv1.x;
                acc[j][5] += xr[j] * wv1.y;
                acc[j][6] += xr[j] * wv1.z;
                acc[j][7] += xr[j] * wv1.w;
            }
        }
    }

    // epilogue: fp16 h store + fused fp32 attention projections
    float4 as0 = *(const float4*)(a_src + tc * 4);
    float4 as1 = *(const float4*)(a_src + 64 + tc * 4);
    float4 ad0 = *(const float4*)(a_dst + tc * 4);
    float4 ad1 = *(const float4*)(a_dst + 64 + tc * 4);
    int headA = tc >> 3;          // cols [0,64): heads 0/1
    int headB = 2 + (tc >> 3);    // cols [64,128): heads 2/3
    #pragma unroll
    for (int j = 0; j < 4; j++) {
        int rr = row0 + tr * 4 + j;
        float psa = acc[j][0] * as0.x + acc[j][1] * as0.y + acc[j][2] * as0.z + acc[j][3] * as0.w;
        float psb = acc[j][4] * as1.x + acc[j][5] * as1.y + acc[j][6] * as1.z + acc[j][7] * as1.w;
        float pda = acc[j][0] * ad0.x + acc[j][1] * ad0.y + acc[j][2] * ad0.z + acc[j][3] * ad0.w;
        float pdb = acc[j][4] * ad1.x + acc[j][5] * ad1.y + acc[j][6] * ad1.z + acc[j][7] * ad1.w;
        psa += __shfl_xor(psa, 1); psb += __shfl_xor(psb, 1);
        pda += __shfl_xor(pda, 1); pdb += __shfl_xor(pdb, 1);
        psa += __shfl_xor(psa, 2); psb += __shfl_xor(psb, 2);
        pda += __shfl_xor(pda, 2); pdb += __shfl_xor(pdb, 2);
        psa += __shfl_xor(psa, 4); psb += __shfl_xor(psb, 4);
        pda += __shfl_xor(pda, 4); pdb += __shfl_xor(pdb, 4);
        if (rr < NN) {
            *(float2*)(h + (size_t)rr * 128 + tc * 4) =
                pack4h(acc[j][0], acc[j][1], acc[j][2], acc[j][3]);
            *(float2*)(h + (size_t)rr * 128 + 64 + tc * 4) =
                pack4h(acc[j][4], acc[j][5], acc[j][6], acc[j][7]);
            if ((tc & 7) == 0) {
                als[rr * 4 + headA] = psa;
                als[rr * 4 + headB] = psb;
                ald[rr * 4 + headA] = pda;
                ald[rr * 4 + headB] = pdb;
            }
        }
    }
}

// ---------------- per-node softmax aggregation (fp16 h gathers) ----------------
// one wave/node; lane = (sub 0..3 edge slot, cg 0..15 channel group of 8)
// gather 16 B (8 halves) per lane per edge; weights/accum fp32
__launch_bounds__(256)
__global__ void agg_kernel(const __half* __restrict__ h, const float* __restrict__ als_,
                           const float* __restrict__ ald_, const int* __restrict__ row_start,
                           const int* __restrict__ src_sorted, const float* __restrict__ bias,
                           float* __restrict__ out) {
    __shared__ float lds_p[4][4][68];   // [wave][head][edge]
    __shared__ int   lds_s[4][64];
    int wid = threadIdx.x >> 6;
    int lane = threadIdx.x & 63;
    int node = blockIdx.x * 4 + wid;
    if (node >= NN) return;
    int sub  = lane >> 4;    // edge slot
    int cg   = lane & 15;    // channel group
    int c0   = cg * 8;
    int head = cg >> 2;

    int start = row_start[node], end = row_start[node + 1];
    float4 adv = *(const float4*)(ald_ + (size_t)node * 4);
    float4 avs = *(const float4*)(als_ + (size_t)node * 4);

    // self-loop (sub==0 only; sub-reduced at the end)
    float p_self = __expf(lrelu(sel4(avs, head) + sel4(adv, head)));
    float pinit = (sub == 0) ? p_self : 0.f;
    float s_sum = pinit;
    float acc[8];
    {
        float4 raw = *(const float4*)(h + (size_t)node * 128 + c0);
        const __half2* q2 = (const __half2*)&raw;
        #pragma unroll
        for (int i = 0; i < 4; i++) {
            float2 f = __half22float2(q2[i]);
            acc[2 * i] = f.x * pinit;
            acc[2 * i + 1] = f.y * pinit;
        }
    }

    for (int base = start; base < end; base += 64) {
        int j = base + lane;
        int my = 0;
        float4 p4 = make_float4(0.f, 0.f, 0.f, 0.f);
        if (j < end) {
            my = src_sorted[j];
            float4 av = *(const float4*)(als_ + (size_t)my * 4);
            p4.x = __expf(lrelu(av.x + adv.x));
            p4.y = __expf(lrelu(av.y + adv.y));
            p4.z = __expf(lrelu(av.z + adv.z));
            p4.w = __expf(lrelu(av.w + adv.w));
        }
        lds_s[wid][lane] = my;
        lds_p[wid][0][lane] = p4.x;
        lds_p[wid][1][lane] = p4.y;
        lds_p[wid][2][lane] = p4.z;
        lds_p[wid][3][lane] = p4.w;
        __builtin_amdgcn_wave_barrier();

        int cnt = end - base;
        if (cnt > 64) cnt = 64;
        for (int jj = 0; jj < cnt; jj += 16) {
            int   s[4];
            float p[4];
            #pragma unroll
            for (int i = 0; i < 4; i++) {
                int e = jj + 4 * i + sub;
                bool v = e < cnt;
                int ec = v ? e : 0;
                s[i] = lds_s[wid][ec];
                float pv = lds_p[wid][head][ec];
                p[i] = v ? pv : 0.f;
            }
            float4 raw[4];
            #pragma unroll
            for (int i = 0; i < 4; i++)
                raw[i] = *(const float4*)(h + (size_t)s[i] * 128 + c0);
            #pragma unroll
            for (int i = 0; i < 4; i++) {
                const __half2* q2 = (const __half2*)&raw[i];
                float2 f0 = __half22float2(q2[0]);
                float2 f1 = __half22float2(q2[1]);
                float2 f2 = __half22float2(q2[2]);
                float2 f3 = __half22float2(q2[3]);
                s_sum += p[i];
                acc[0] += f0.x * p[i]; acc[1] += f0.y * p[i];
                acc[2] += f1.x * p[i]; acc[3] += f1.y * p[i];
                acc[4] += f2.x * p[i]; acc[5] += f2.y * p[i];
                acc[6] += f3.x * p[i]; acc[7] += f3.y * p[i];
            }
        }
        __builtin_amdgcn_wave_barrier();
    }

    // reduce partial sums across the 4 edge slots (lane bits 4,5)
    #pragma unroll
    for (int i = 0; i < 8; i++) {
        acc[i] += __shfl_xor(acc[i], 16);
        acc[i] += __shfl_xor(acc[i], 32);
    }
    s_sum += __shfl_xor(s_sum, 16);
    s_sum += __shfl_xor(s_sum, 32);

    float invs = 1.0f / (s_sum + 1e-16f);
    // each lane outputs channels c0 + 2*sub, c0 + 2*sub + 1 (parallel gelu)
    float t0 = (sub & 1) ? acc[2] : acc[0];
    float t1 = (sub & 1) ? acc[6] : acc[4];
    float num0 = (sub & 2) ? t1 : t0;
    float u0 = (sub & 1) ? acc[3] : acc[1];
    float u1 = (sub & 1) ? acc[7] : acc[5];
    float num1 = (sub & 2) ? u1 : u0;
    int cc = c0 + 2 * sub;
    float2 bv = *(const float2*)(bias + cc);
    float o0 = gelu_f(num0 * invs + bv.x);
    float o1 = gelu_f(num1 * invs + bv.y);
    *(float2*)(out + (size_t)node * 128 + cc) = make_float2(o0, o1);
}

extern "C" void kernel_launch(void* const* d_in, const int* in_sizes, int n_in,
                              void* d_out, int out_size, void* d_ws, size_t ws_size,
                              hipStream_t stream) {
    const int*   label = (const int*)d_in[0];
    const int*   eidx  = (const int*)d_in[1];          // [2, NE]
    const float* rq    = (const float*)d_in[3];
    const float* emb   = (const float*)d_in[4];
    const float* reqW  = (const float*)d_in[5];
    const float* reqb  = (const float*)d_in[6];
    const float* W[3]    = {(const float*)d_in[7],  (const float*)d_in[11], (const float*)d_in[15]};
    const float* asrc[3] = {(const float*)d_in[8],  (const float*)d_in[12], (const float*)d_in[16]};
    const float* adst[3] = {(const float*)d_in[9],  (const float*)d_in[13], (const float*)d_in[17]};
    const float* bias[3] = {(const float*)d_in[10], (const float*)d_in[14], (const float*)d_in[18]};

    const int* e_src = eidx;
    const int* e_dst = eidx + NE;

    char* ws = (char*)d_ws;
    size_t off = 0;
    auto A = [&](size_t n) { size_t o = off; off += (n + 255) & ~(size_t)255; return o; };
    size_t o_deg   = A((size_t)NN * 4);        // zeroed
    size_t o_stats = A(8);                     // zeroed
    size_t zero_bytes = off;
    size_t o_row   = A((size_t)(NN + 1) * 4);
    size_t o_bsum  = A(256 * 4);
    size_t o_srcS  = A((size_t)NE * 4);
    size_t o_x     = A((size_t)NN * 128 * 4);
    size_t o_h     = A((size_t)NN * 128 * 2);  // fp16
    size_t o_als   = A((size_t)NN * 4 * 4);
    size_t o_ald   = A((size_t)NN * 4 * 4);
    (void)ws_size; (void)n_in; (void)in_sizes; (void)out_size;

    int*    deg    = (int*)(ws + o_deg);
    float*  stats  = (float*)(ws + o_stats);
    int*    rowst  = (int*)(ws + o_row);
    int*    bsum   = (int*)(ws + o_bsum);
    int*    srcS   = (int*)(ws + o_srcS);
    float*  x      = (float*)(ws + o_x);
    __half* h      = (__half*)(ws + o_h);
    float*  als    = (float*)(ws + o_als);
    float*  ald    = (float*)(ws + o_ald);

    hipMemsetAsync(ws, 0, zero_bytes, stream);

    // fused frontend stats + degree histogram
    stats_hist_kernel<<<STATS_BLOCKS + (NE + 255) / 256, 256, 0, stream>>>(rq, stats, e_dst, deg);

    // CSR build (self-loops handled analytically in agg)
    const int nb_scan = (NN + 255) / 256;  // 196
    scan1_kernel<<<nb_scan, 256, 0, stream>>>(deg, rowst, bsum);
    scan2_kernel<<<1, 256, 0, stream>>>(bsum, nb_scan);
    scan3_kernel<<<nb_scan, 256, 0, stream>>>(rowst, bsum);
    scatter_kernel<<<(NE + 255) / 256, 256, 0, stream>>>(e_src, e_dst, rowst, deg, srcS);

    // 3 GAT layers
    const int gemm_blocks = (NN + 63) / 64;        // 782
    const int agg_blocks = (NN + 3) / 4;           // 12500
    for (int l = 0; l < 3; l++) {
        if (l == 0)
            gemm_al_kernel<1><<<gemm_blocks, 256, 0, stream>>>(x, W[l], asrc[l], adst[l], h, als, ald,
                                                               label, rq, emb, reqW, reqb, stats);
        else
            gemm_al_kernel<0><<<gemm_blocks, 256, 0, stream>>>(x, W[l], asrc[l], adst[l], h, als, ald,
                                                               label, rq, emb, reqW, reqb, stats);
        float* dst_buf = (l == 2) ? (float*)d_out : x;
        agg_kernel<<<agg_blocks, 256, 0, stream>>>(h, als, ald, rowst, srcS, bias[l], dst_buf);
    }
}

// Round 7
// 372.334 us; speedup vs baseline: 1.3422x; 1.0177x over previous
//
#include <hip/hip_runtime.h>
#include <hip/hip_fp16.h>
#include <math.h>

#define NN 50000
#define NE 800000
#define HC 128
#define NHEAD 4
#define EMB 64
#define STATS_BLOCKS 64

typedef _Float16 f16x8 __attribute__((ext_vector_type(8)));
typedef float f32x4 __attribute__((ext_vector_type(4)));

__device__ __forceinline__ float lrelu(float x) { return x > 0.0f ? x : 0.2f * x; }
__device__ __forceinline__ float gelu_f(float x) {
    return 0.5f * x * (1.0f + erff(x * 0.70710678118654752440f));
}
__device__ __forceinline__ float sel4(float4 v, int h) {
    float r = v.x;
    r = (h == 1) ? v.y : r;
    r = (h == 2) ? v.z : r;
    r = (h == 3) ? v.w : r;
    return r;
}
__device__ __forceinline__ f16x8 cvt8(float4 a, float4 b) {
    f16x8 v;
    v[0] = (_Float16)a.x; v[1] = (_Float16)a.y; v[2] = (_Float16)a.z; v[3] = (_Float16)a.w;
    v[4] = (_Float16)b.x; v[5] = (_Float16)b.y; v[6] = (_Float16)b.z; v[7] = (_Float16)b.w;
    return v;
}

// ---------------- fused frontend stats + degree histogram ----------------
__global__ void stats_hist_kernel(const float* __restrict__ rq, float* __restrict__ stats,
                                  const int* __restrict__ dst, int* __restrict__ deg) {
    if (blockIdx.x < STATS_BLOCKS) {
        int i = blockIdx.x * 256 + threadIdx.x;
        float s = 0.f, s2 = 0.f;
        for (; i < NN; i += STATS_BLOCKS * 256) {
            float v = rq[i];
            s += v; s2 += v * v;
        }
        #pragma unroll
        for (int off = 32; off > 0; off >>= 1) {
            s  += __shfl_down(s, off);
            s2 += __shfl_down(s2, off);
        }
        __shared__ float ls[4], ls2[4];
        int lane = threadIdx.x & 63, wid = threadIdx.x >> 6;
        if (lane == 0) { ls[wid] = s; ls2[wid] = s2; }
        __syncthreads();
        if (threadIdx.x == 0) {
            atomicAdd(&stats[0], ls[0] + ls[1] + ls[2] + ls[3]);
            atomicAdd(&stats[1], ls2[0] + ls2[1] + ls2[2] + ls2[3]);
        }
    } else {
        int i = (blockIdx.x - STATS_BLOCKS) * 256 + threadIdx.x;
        if (i < NE) atomicAdd(&deg[dst[i]], 1);
    }
}

// ---------------- CSR build ----------------
__global__ void scan1_kernel(const int* __restrict__ deg, int* __restrict__ row_excl,
                             int* __restrict__ bsum) {
    __shared__ int tmp[256];
    int t = threadIdx.x;
    int i = blockIdx.x * 256 + t;
    int v = (i < NN) ? deg[i] : 0;
    tmp[t] = v;
    __syncthreads();
    #pragma unroll
    for (int off = 1; off < 256; off <<= 1) {
        int add = (t >= off) ? tmp[t - off] : 0;
        __syncthreads();
        tmp[t] += add;
        __syncthreads();
    }
    if (i < NN) row_excl[i] = tmp[t] - v;
    if (t == 255) bsum[blockIdx.x] = tmp[255];
}

__global__ void scan2_kernel(int* __restrict__ bsum, int nb) {
    __shared__ int tmp[256];
    int t = threadIdx.x;
    int v = (t < nb) ? bsum[t] : 0;
    tmp[t] = v;
    __syncthreads();
    #pragma unroll
    for (int off = 1; off < 256; off <<= 1) {
        int add = (t >= off) ? tmp[t - off] : 0;
        __syncthreads();
        tmp[t] += add;
        __syncthreads();
    }
    if (t < nb) bsum[t] = tmp[t] - v;  // exclusive block offsets
}

__global__ void scan3_kernel(int* __restrict__ row_excl, const int* __restrict__ bsum) {
    int i = blockIdx.x * blockDim.x + threadIdx.x;
    if (i < NN) row_excl[i] += bsum[i >> 8];
    if (i == 0) row_excl[NN] = NE;
}

// fills segments back-to-front via atomicSub on deg (deg ends at 0; not reused)
__global__ void scatter_kernel(const int* __restrict__ src, const int* __restrict__ dst,
                               const int* __restrict__ row_start, int* __restrict__ deg,
                               int* __restrict__ src_sorted) {
    int i = blockIdx.x * blockDim.x + threadIdx.x;
    if (i < NE) {
        int d = dst[i];
        int pos = row_start[d] + atomicSub(&deg[d], 1) - 1;
        src_sorted[pos] = src[i];
    }
}

// ---- fused MFMA GEMM + attention projections: h(fp16) = x@W ; als/ald fp32 ----
// 256 thr = 4 waves; tile M=64 (16/wave) x N=128 x K=128; v_mfma_f32_16x16x32_f16.
// A-frag: A[m=lane&15][k=quad*8+j]; B-frag: B[k=quad*8+j][n=lane&15] (sWt = W^T);
// C/D: D[m=quad*4+reg][n=lane&15]. als/ald computed fp32 from accumulators.
template <int L0>
__launch_bounds__(256)
__global__ void gemm_al_kernel(const __half* __restrict__ xh, const float* __restrict__ W,
                               const float* __restrict__ a_src, const float* __restrict__ a_dst,
                               __half* __restrict__ h, float* __restrict__ als,
                               float* __restrict__ ald,
                               const int* __restrict__ label, const float* __restrict__ rq,
                               const float* __restrict__ emb, const float* __restrict__ reqW,
                               const float* __restrict__ reqb, const float* __restrict__ stats) {
    __shared__ _Float16 sX[64][136];    // 17.4 KB (pad 136: b128-friendly)
    __shared__ _Float16 sWt[128][136];  // 34.8 KB, W transposed [n][k]
    int t = threadIdx.x;
    int w = t >> 6, l = t & 63;
    int col = l & 15, quad = l >> 4;
    int row0 = blockIdx.x * 64;

    // stage W^T fp16
    #pragma unroll
    for (int i = 0; i < 16; i++) {
        int idx = t + 256 * i;        // 0..4095 float4s of W
        int k = idx >> 5;             // 0..127
        int n4 = (idx & 31) * 4;
        float4 wv = ((const float4*)W)[idx];
        sWt[n4 + 0][k] = (_Float16)wv.x;
        sWt[n4 + 1][k] = (_Float16)wv.y;
        sWt[n4 + 2][k] = (_Float16)wv.z;
        sWt[n4 + 3][k] = (_Float16)wv.w;
    }
    // stage x tile fp16
    float mean = 0.f, inv = 0.f;
    if (L0) {
        float sum = stats[0], sumsq = stats[1];
        mean = sum / (float)NN;
        float var = (sumsq - sum * sum / (float)NN) / (float)(NN - 1);
        inv = 1.0f / (sqrtf(var) + 1e-6f);
    }
    #pragma unroll
    for (int i = 0; i < 4; i++) {
        int idx = t + 256 * i;   // 0..1023 8-half units
        int r = idx >> 4;        // 0..63
        int q = idx & 15;        // unit within row
        int rr = row0 + r;
        f16x8 v;
        #pragma unroll
        for (int j = 0; j < 8; j++) v[j] = (_Float16)0.f;
        if (rr < NN) {
            if (L0) {
                if (q < 8) {
                    const float4* er = (const float4*)(emb + (size_t)label[rr] * EMB);
                    v = cvt8(er[q * 2], er[q * 2 + 1]);
                } else {
                    int j4 = (q - 8) * 2;
                    float4 w0 = ((const float4*)reqW)[j4],     b0 = ((const float4*)reqb)[j4];
                    float4 w1 = ((const float4*)reqW)[j4 + 1], b1 = ((const float4*)reqb)[j4 + 1];
                    float r2 = (rq[rr] - mean) * inv;
                    v = cvt8(make_float4(r2 * w0.x + b0.x, r2 * w0.y + b0.y,
                                         r2 * w0.z + b0.z, r2 * w0.w + b0.w),
                             make_float4(r2 * w1.x + b1.x, r2 * w1.y + b1.y,
                                         r2 * w1.z + b1.z, r2 * w1.w + b1.w));
                }
            } else {
                v = *(const f16x8*)(xh + (size_t)rr * 128 + q * 8);
            }
        }
        *(f16x8*)&sX[r][q * 8] = v;
    }
    __syncthreads();

    // MFMA K-loop (wave-local rows w*16..w*16+15)
    f32x4 zero = {0.f, 0.f, 0.f, 0.f};
    f32x4 acc[8];
    #pragma unroll
    for (int nt = 0; nt < 8; nt++) acc[nt] = zero;
    f16x8 afr[4];
    #pragma unroll
    for (int ks = 0; ks < 4; ks++)
        afr[ks] = *(const f16x8*)&sX[w * 16 + col][ks * 32 + quad * 8];
    #pragma unroll
    for (int nt = 0; nt < 8; nt++) {
        #pragma unroll
        for (int ks = 0; ks < 4; ks++) {
            f16x8 bfr = *(const f16x8*)&sWt[nt * 16 + col][ks * 32 + quad * 8];
            acc[nt] = __builtin_amdgcn_mfma_f32_16x16x32_f16(afr[ks], bfr, acc[nt], 0, 0, 0);
        }
    }

    // h store: transpose via wave-own sX rows, then coalesced b128 stores
    #pragma unroll
    for (int nt = 0; nt < 8; nt++)
        #pragma unroll
        for (int r = 0; r < 4; r++)
            sX[w * 16 + quad * 4 + r][nt * 16 + col] = (_Float16)acc[nt][r];
    __builtin_amdgcn_wave_barrier();
    #pragma unroll
    for (int i = 0; i < 4; i++) {
        int u = l + 64 * i;          // 0..255
        int r = u >> 4, off = (u & 15) * 8;
        int rr = row0 + w * 16 + r;
        f16x8 v = *(const f16x8*)&sX[w * 16 + r][off];
        if (rr < NN) *(f16x8*)(h + (size_t)rr * 128 + off) = v;
    }

    // attention projections (fp32, from accumulators)
    float as[8], ad[8];
    #pragma unroll
    for (int nt = 0; nt < 8; nt++) {
        as[nt] = a_src[nt * 16 + col];
        ad[nt] = a_dst[nt * 16 + col];
    }
    #pragma unroll
    for (int r = 0; r < 4; r++) {
        float ps[4], pd[4];
        #pragma unroll
        for (int hd = 0; hd < 4; hd++) {
            ps[hd] = acc[2 * hd][r] * as[2 * hd] + acc[2 * hd + 1][r] * as[2 * hd + 1];
            pd[hd] = acc[2 * hd][r] * ad[2 * hd] + acc[2 * hd + 1][r] * ad[2 * hd + 1];
            ps[hd] += __shfl_xor(ps[hd], 1); pd[hd] += __shfl_xor(pd[hd], 1);
            ps[hd] += __shfl_xor(ps[hd], 2); pd[hd] += __shfl_xor(pd[hd], 2);
            ps[hd] += __shfl_xor(ps[hd], 4); pd[hd] += __shfl_xor(pd[hd], 4);
            ps[hd] += __shfl_xor(ps[hd], 8); pd[hd] += __shfl_xor(pd[hd], 8);
        }
        int rr = row0 + w * 16 + quad * 4 + r;
        if (col == 0 && rr < NN) {
            *(float4*)(als + (size_t)rr * 4) = make_float4(ps[0], ps[1], ps[2], ps[3]);
            *(float4*)(ald + (size_t)rr * 4) = make_float4(pd[0], pd[1], pd[2], pd[3]);
        }
    }
}

// ---------------- per-node softmax aggregation (fp16 h gathers) ----------------
// one wave/node; lane = (sub 0..3 edge slot, cg 0..15 channel group of 8)
// FINAL=0: write fp16 x for next layer; FINAL=1: write fp32 d_out
template <int FINAL>
__launch_bounds__(256)
__global__ void agg_kernel(const __half* __restrict__ h, const float* __restrict__ als_,
                           const float* __restrict__ ald_, const int* __restrict__ row_start,
                           const int* __restrict__ src_sorted, const float* __restrict__ bias,
                           float* __restrict__ outf, __half* __restrict__ outh) {
    __shared__ float lds_p[4][4][68];   // [wave][head][edge]
    __shared__ int   lds_s[4][64];
    int wid = threadIdx.x >> 6;
    int lane = threadIdx.x & 63;
    int node = blockIdx.x * 4 + wid;
    if (node >= NN) return;
    int sub  = lane >> 4;    // edge slot
    int cg   = lane & 15;    // channel group
    int c0   = cg * 8;
    int head = cg >> 2;

    int start = row_start[node], end = row_start[node + 1];
    float4 adv = *(const float4*)(ald_ + (size_t)node * 4);
    float4 avs = *(const float4*)(als_ + (size_t)node * 4);

    // self-loop (sub==0 only; sub-reduced at the end)
    float p_self = __expf(lrelu(sel4(avs, head) + sel4(adv, head)));
    float pinit = (sub == 0) ? p_self : 0.f;
    float s_sum = pinit;
    float acc[8];
    {
        float4 raw = *(const float4*)(h + (size_t)node * 128 + c0);
        const __half2* q2 = (const __half2*)&raw;
        #pragma unroll
        for (int i = 0; i < 4; i++) {
            float2 f = __half22float2(q2[i]);
            acc[2 * i] = f.x * pinit;
            acc[2 * i + 1] = f.y * pinit;
        }
    }

    for (int base = start; base < end; base += 64) {
        int j = base + lane;
        int my = 0;
        float4 p4 = make_float4(0.f, 0.f, 0.f, 0.f);
        if (j < end) {
            my = src_sorted[j];
            float4 av = *(const float4*)(als_ + (size_t)my * 4);
            p4.x = __expf(lrelu(av.x + adv.x));
            p4.y = __expf(lrelu(av.y + adv.y));
            p4.z = __expf(lrelu(av.z + adv.z));
            p4.w = __expf(lrelu(av.w + adv.w));
        }
        lds_s[wid][lane] = my;
        lds_p[wid][0][lane] = p4.x;
        lds_p[wid][1][lane] = p4.y;
        lds_p[wid][2][lane] = p4.z;
        lds_p[wid][3][lane] = p4.w;
        __builtin_amdgcn_wave_barrier();

        int cnt = end - base;
        if (cnt > 64) cnt = 64;
        for (int jj = 0; jj < cnt; jj += 16) {
            int   s[4];
            float p[4];
            #pragma unroll
            for (int i = 0; i < 4; i++) {
                int e = jj + 4 * i + sub;
                bool v = e < cnt;
                int ec = v ? e : 0;
                s[i] = lds_s[wid][ec];
                float pv = lds_p[wid][head][ec];
                p[i] = v ? pv : 0.f;
            }
            float4 raw[4];
            #pragma unroll
            for (int i = 0; i < 4; i++)
                raw[i] = *(const float4*)(h + (size_t)s[i] * 128 + c0);
            #pragma unroll
            for (int i = 0; i < 4; i++) {
                const __half2* q2 = (const __half2*)&raw[i];
                float2 f0 = __half22float2(q2[0]);
                float2 f1 = __half22float2(q2[1]);
                float2 f2 = __half22float2(q2[2]);
                float2 f3 = __half22float2(q2[3]);
                s_sum += p[i];
                acc[0] += f0.x * p[i]; acc[1] += f0.y * p[i];
                acc[2] += f1.x * p[i]; acc[3] += f1.y * p[i];
                acc[4] += f2.x * p[i]; acc[5] += f2.y * p[i];
                acc[6] += f3.x * p[i]; acc[7] += f3.y * p[i];
            }
        }
        __builtin_amdgcn_wave_barrier();
    }

    // reduce partial sums across the 4 edge slots (lane bits 4,5)
    #pragma unroll
    for (int i = 0; i < 8; i++) {
        acc[i] += __shfl_xor(acc[i], 16);
        acc[i] += __shfl_xor(acc[i], 32);
    }
    s_sum += __shfl_xor(s_sum, 16);
    s_sum += __shfl_xor(s_sum, 32);

    float invs = 1.0f / (s_sum + 1e-16f);
    // each lane outputs channels c0 + 2*sub, c0 + 2*sub + 1 (parallel gelu)
    float t0 = (sub & 1) ? acc[2] : acc[0];
    float t1 = (sub & 1) ? acc[6] : acc[4];
    float num0 = (sub & 2) ? t1 : t0;
    float u0 = (sub & 1) ? acc[3] : acc[1];
    float u1 = (sub & 1) ? acc[7] : acc[5];
    float num1 = (sub & 2) ? u1 : u0;
    int cc = c0 + 2 * sub;
    float2 bv = *(const float2*)(bias + cc);
    float o0 = gelu_f(num0 * invs + bv.x);
    float o1 = gelu_f(num1 * invs + bv.y);
    if (FINAL) {
        *(float2*)(outf + (size_t)node * 128 + cc) = make_float2(o0, o1);
    } else {
        *(__half2*)(outh + (size_t)node * 128 + cc) = __floats2half2_rn(o0, o1);
    }
}

extern "C" void kernel_launch(void* const* d_in, const int* in_sizes, int n_in,
                              void* d_out, int out_size, void* d_ws, size_t ws_size,
                              hipStream_t stream) {
    const int*   label = (const int*)d_in[0];
    const int*   eidx  = (const int*)d_in[1];          // [2, NE]
    const float* rq    = (const float*)d_in[3];
    const float* emb   = (const float*)d_in[4];
    const float* reqW  = (const float*)d_in[5];
    const float* reqb  = (const float*)d_in[6];
    const float* W[3]    = {(const float*)d_in[7],  (const float*)d_in[11], (const float*)d_in[15]};
    const float* asrc[3] = {(const float*)d_in[8],  (const float*)d_in[12], (const float*)d_in[16]};
    const float* adst[3] = {(const float*)d_in[9],  (const float*)d_in[13], (const float*)d_in[17]};
    const float* bias[3] = {(const float*)d_in[10], (const float*)d_in[14], (const float*)d_in[18]};

    const int* e_src = eidx;
    const int* e_dst = eidx + NE;

    char* ws = (char*)d_ws;
    size_t off = 0;
    auto A = [&](size_t n) { size_t o = off; off += (n + 255) & ~(size_t)255; return o; };
    size_t o_deg   = A((size_t)NN * 4);        // zeroed
    size_t o_stats = A(8);                     // zeroed
    size_t zero_bytes = off;
    size_t o_row   = A((size_t)(NN + 1) * 4);
    size_t o_bsum  = A(256 * 4);
    size_t o_srcS  = A((size_t)NE * 4);
    size_t o_x     = A((size_t)NN * 128 * 2);  // fp16
    size_t o_h     = A((size_t)NN * 128 * 2);  // fp16
    size_t o_als   = A((size_t)NN * 4 * 4);
    size_t o_ald   = A((size_t)NN * 4 * 4);
    (void)ws_size; (void)n_in; (void)in_sizes; (void)out_size;

    int*    deg    = (int*)(ws + o_deg);
    float*  stats  = (float*)(ws + o_stats);
    int*    rowst  = (int*)(ws + o_row);
    int*    bsum   = (int*)(ws + o_bsum);
    int*    srcS   = (int*)(ws + o_srcS);
    __half* xh     = (__half*)(ws + o_x);
    __half* h      = (__half*)(ws + o_h);
    float*  als    = (float*)(ws + o_als);
    float*  ald    = (float*)(ws + o_ald);

    (void)hipMemsetAsync(ws, 0, zero_bytes, stream);

    // fused frontend stats + degree histogram
    stats_hist_kernel<<<STATS_BLOCKS + (NE + 255) / 256, 256, 0, stream>>>(rq, stats, e_dst, deg);

    // CSR build (self-loops handled analytically in agg)
    const int nb_scan = (NN + 255) / 256;  // 196
    scan1_kernel<<<nb_scan, 256, 0, stream>>>(deg, rowst, bsum);
    scan2_kernel<<<1, 256, 0, stream>>>(bsum, nb_scan);
    scan3_kernel<<<nb_scan, 256, 0, stream>>>(rowst, bsum);
    scatter_kernel<<<(NE + 255) / 256, 256, 0, stream>>>(e_src, e_dst, rowst, deg, srcS);

    // 3 GAT layers
    const int gemm_blocks = (NN + 63) / 64;        // 782
    const int agg_blocks = (NN + 3) / 4;           // 12500
    for (int l = 0; l < 3; l++) {
        if (l == 0)
            gemm_al_kernel<1><<<gemm_blocks, 256, 0, stream>>>(xh, W[l], asrc[l], adst[l], h, als, ald,
                                                               label, rq, emb, reqW, reqb, stats);
        else
            gemm_al_kernel<0><<<gemm_blocks, 256, 0, stream>>>(xh, W[l], asrc[l], adst[l], h, als, ald,
                                                               label, rq, emb, reqW, reqb, stats);
        if (l == 2)
            agg_kernel<1><<<agg_blocks, 256, 0, stream>>>(h, als, ald, rowst, srcS, bias[l],
                                                          (float*)d_out, nullptr);
        else
            agg_kernel<0><<<agg_blocks, 256, 0, stream>>>(h, als, ald, rowst, srcS, bias[l],
                                                          nullptr, xh);
    }
}

// Round 8
// 323.414 us; speedup vs baseline: 1.5453x; 1.1513x over previous
//
#include <hip/hip_runtime.h>
#include <hip/hip_fp16.h>
#include <math.h>

#define NN 50000
#define NE 800000
#define HC 128
#define NHEAD 4
#define EMB 64
#define STATS_BLOCKS 64
#define NB 196          // buckets of 256 nodes
#define HIST_BLOCKS 196 // ceil(NE/4096)

typedef _Float16 f16x8 __attribute__((ext_vector_type(8)));
typedef float f32x4 __attribute__((ext_vector_type(4)));

__device__ __forceinline__ float lrelu(float x) { return x > 0.0f ? x : 0.2f * x; }
__device__ __forceinline__ float gelu_f(float x) {
    return 0.5f * x * (1.0f + erff(x * 0.70710678118654752440f));
}
__device__ __forceinline__ float sel4(float4 v, int h) {
    float r = v.x;
    r = (h == 1) ? v.y : r;
    r = (h == 2) ? v.z : r;
    r = (h == 3) ? v.w : r;
    return r;
}
__device__ __forceinline__ f16x8 cvt8(float4 a, float4 b) {
    f16x8 v;
    v[0] = (_Float16)a.x; v[1] = (_Float16)a.y; v[2] = (_Float16)a.z; v[3] = (_Float16)a.w;
    v[4] = (_Float16)b.x; v[5] = (_Float16)b.y; v[6] = (_Float16)b.z; v[7] = (_Float16)b.w;
    return v;
}

// ------- fused frontend stats + LDS-binned bucket histogram (bucket = dst>>8) -------
__global__ void stats_hist_kernel(const float* __restrict__ rq, float* __restrict__ stats,
                                  const int* __restrict__ dst, int* __restrict__ bucketCnt) {
    __shared__ float ls[4], ls2[4];
    __shared__ int cnt[NB];
    if (blockIdx.x < STATS_BLOCKS) {
        int i = blockIdx.x * 256 + threadIdx.x;
        float s = 0.f, s2 = 0.f;
        for (; i < NN; i += STATS_BLOCKS * 256) {
            float v = rq[i];
            s += v; s2 += v * v;
        }
        #pragma unroll
        for (int off = 32; off > 0; off >>= 1) {
            s  += __shfl_down(s, off);
            s2 += __shfl_down(s2, off);
        }
        int lane = threadIdx.x & 63, wid = threadIdx.x >> 6;
        if (lane == 0) { ls[wid] = s; ls2[wid] = s2; }
        __syncthreads();
        if (threadIdx.x == 0) {
            atomicAdd(&stats[0], ls[0] + ls[1] + ls[2] + ls[3]);
            atomicAdd(&stats[1], ls2[0] + ls2[1] + ls2[2] + ls2[3]);
        }
    } else {
        int bb = blockIdx.x - STATS_BLOCKS;
        for (int i = threadIdx.x; i < NB; i += 256) cnt[i] = 0;
        __syncthreads();
        int base = bb * 4096;
        #pragma unroll
        for (int it = 0; it < 16; it++) {
            int i = base + it * 256 + threadIdx.x;
            if (i < NE) atomicAdd(&cnt[dst[i] >> 8], 1);
        }
        __syncthreads();
        for (int i = threadIdx.x; i < NB; i += 256)
            if (cnt[i]) atomicAdd(&bucketCnt[i], cnt[i]);
    }
}

// ------- exclusive scan of bucket counts -> bucketBase[0..NB], cursors -------
__global__ void bucket_scan_kernel(const int* __restrict__ bucketCnt, int* __restrict__ bucketBase,
                                   int* __restrict__ bucketCursor) {
    __shared__ int tmp[256];
    int t = threadIdx.x;
    int v = (t < NB) ? bucketCnt[t] : 0;
    tmp[t] = v;
    __syncthreads();
    #pragma unroll
    for (int off = 1; off < 256; off <<= 1) {
        int add = (t >= off) ? tmp[t - off] : 0;
        __syncthreads();
        tmp[t] += add;
        __syncthreads();
    }
    int excl = tmp[t] - v;
    if (t <= NB) bucketBase[t] = excl;
    if (t < NB) bucketCursor[t] = excl;
}

// ------- binA: partition edges into bucket regions as (src, dst&255) pairs -------
__global__ void binA_kernel(const int* __restrict__ src, const int* __restrict__ dst,
                            int* __restrict__ bucketCursor, int2* __restrict__ edge_tmp) {
    __shared__ int cnt[NB];
    __shared__ int cur[NB];
    int t = threadIdx.x;
    for (int i = t; i < NB; i += 256) cnt[i] = 0;
    __syncthreads();
    int base = blockIdx.x * 4096;
    int d[16], s[16];
    #pragma unroll
    for (int it = 0; it < 16; it++) {
        int i = base + it * 256 + t;
        bool ok = i < NE;
        d[it] = ok ? dst[i] : -1;
        s[it] = ok ? src[i] : 0;
        if (ok) atomicAdd(&cnt[d[it] >> 8], 1);
    }
    __syncthreads();
    for (int i = t; i < NB; i += 256)
        cur[i] = cnt[i] ? atomicAdd(&bucketCursor[i], cnt[i]) : 0;
    __syncthreads();
    #pragma unroll
    for (int it = 0; it < 16; it++) {
        if (d[it] >= 0) {
            int b = d[it] >> 8;
            int pos = atomicAdd(&cur[b], 1);
            edge_tmp[pos] = make_int2(s[it], d[it] & 255);
        }
    }
}

// ------- binB: per-bucket local counting sort -> row_start + src_sorted -------
__global__ void binB_kernel(const int2* __restrict__ edge_tmp, const int* __restrict__ bucketBase,
                            int* __restrict__ row_start, int* __restrict__ src_sorted) {
    __shared__ int ldeg[256];
    __shared__ int lexcl[256];
    __shared__ int lcur[256];
    int b = blockIdx.x, t = threadIdx.x;
    int base = bucketBase[b], endb = bucketBase[b + 1];
    ldeg[t] = 0;
    __syncthreads();
    for (int i = base + t; i < endb; i += 256)
        atomicAdd(&ldeg[edge_tmp[i].y], 1);
    __syncthreads();
    int v = ldeg[t];
    lexcl[t] = v;
    __syncthreads();
    #pragma unroll
    for (int off = 1; off < 256; off <<= 1) {
        int add = (t >= off) ? lexcl[t - off] : 0;
        __syncthreads();
        lexcl[t] += add;
        __syncthreads();
    }
    int excl = lexcl[t] - v;
    int node = b * 256 + t;
    if (node <= NN) row_start[node] = base + excl;
    lcur[t] = excl;
    __syncthreads();
    for (int i = base + t; i < endb; i += 256) {
        int2 e = edge_tmp[i];
        int pos = atomicAdd(&lcur[e.y], 1);
        src_sorted[base + pos] = e.x;
    }
}

// ---- fused MFMA GEMM + attention projections: h(fp16) = x@W ; als/ald fp32 ----
// 256 thr = 4 waves; tile M=64 (16/wave) x N=128 x K=128; v_mfma_f32_16x16x32_f16.
template <int L0>
__launch_bounds__(256)
__global__ void gemm_al_kernel(const __half* __restrict__ xh, const float* __restrict__ W,
                               const float* __restrict__ a_src, const float* __restrict__ a_dst,
                               __half* __restrict__ h, float* __restrict__ als,
                               float* __restrict__ ald,
                               const int* __restrict__ label, const float* __restrict__ rq,
                               const float* __restrict__ emb, const float* __restrict__ reqW,
                               const float* __restrict__ reqb, const float* __restrict__ stats) {
    __shared__ _Float16 sX[64][136];    // 17.4 KB
    __shared__ _Float16 sWt[128][136];  // 34.8 KB, W transposed [n][k]
    int t = threadIdx.x;
    int w = t >> 6, l = t & 63;
    int col = l & 15, quad = l >> 4;
    int row0 = blockIdx.x * 64;

    #pragma unroll
    for (int i = 0; i < 16; i++) {
        int idx = t + 256 * i;        // 0..4095 float4s of W
        int k = idx >> 5;             // 0..127
        int n4 = (idx & 31) * 4;
        float4 wv = ((const float4*)W)[idx];
        sWt[n4 + 0][k] = (_Float16)wv.x;
        sWt[n4 + 1][k] = (_Float16)wv.y;
        sWt[n4 + 2][k] = (_Float16)wv.z;
        sWt[n4 + 3][k] = (_Float16)wv.w;
    }
    float mean = 0.f, inv = 0.f;
    if (L0) {
        float sum = stats[0], sumsq = stats[1];
        mean = sum / (float)NN;
        float var = (sumsq - sum * sum / (float)NN) / (float)(NN - 1);
        inv = 1.0f / (sqrtf(var) + 1e-6f);
    }
    #pragma unroll
    for (int i = 0; i < 4; i++) {
        int idx = t + 256 * i;   // 0..1023 8-half units
        int r = idx >> 4;        // 0..63
        int q = idx & 15;
        int rr = row0 + r;
        f16x8 v;
        #pragma unroll
        for (int j = 0; j < 8; j++) v[j] = (_Float16)0.f;
        if (rr < NN) {
            if (L0) {
                if (q < 8) {
                    const float4* er = (const float4*)(emb + (size_t)label[rr] * EMB);
                    v = cvt8(er[q * 2], er[q * 2 + 1]);
                } else {
                    int j4 = (q - 8) * 2;
                    float4 w0 = ((const float4*)reqW)[j4],     b0 = ((const float4*)reqb)[j4];
                    float4 w1 = ((const float4*)reqW)[j4 + 1], b1 = ((const float4*)reqb)[j4 + 1];
                    float r2 = (rq[rr] - mean) * inv;
                    v = cvt8(make_float4(r2 * w0.x + b0.x, r2 * w0.y + b0.y,
                                         r2 * w0.z + b0.z, r2 * w0.w + b0.w),
                             make_float4(r2 * w1.x + b1.x, r2 * w1.y + b1.y,
                                         r2 * w1.z + b1.z, r2 * w1.w + b1.w));
                }
            } else {
                v = *(const f16x8*)(xh + (size_t)rr * 128 + q * 8);
            }
        }
        *(f16x8*)&sX[r][q * 8] = v;
    }
    __syncthreads();

    f32x4 zero = {0.f, 0.f, 0.f, 0.f};
    f32x4 acc[8];
    #pragma unroll
    for (int nt = 0; nt < 8; nt++) acc[nt] = zero;
    f16x8 afr[4];
    #pragma unroll
    for (int ks = 0; ks < 4; ks++)
        afr[ks] = *(const f16x8*)&sX[w * 16 + col][ks * 32 + quad * 8];
    #pragma unroll
    for (int nt = 0; nt < 8; nt++) {
        #pragma unroll
        for (int ks = 0; ks < 4; ks++) {
            f16x8 bfr = *(const f16x8*)&sWt[nt * 16 + col][ks * 32 + quad * 8];
            acc[nt] = __builtin_amdgcn_mfma_f32_16x16x32_f16(afr[ks], bfr, acc[nt], 0, 0, 0);
        }
    }

    // h store: transpose via wave-own sX rows, then coalesced b128 stores
    #pragma unroll
    for (int nt = 0; nt < 8; nt++)
        #pragma unroll
        for (int r = 0; r < 4; r++)
            sX[w * 16 + quad * 4 + r][nt * 16 + col] = (_Float16)acc[nt][r];
    __builtin_amdgcn_wave_barrier();
    #pragma unroll
    for (int i = 0; i < 4; i++) {
        int u = l + 64 * i;          // 0..255
        int r = u >> 4, off = (u & 15) * 8;
        int rr = row0 + w * 16 + r;
        f16x8 v = *(const f16x8*)&sX[w * 16 + r][off];
        if (rr < NN) *(f16x8*)(h + (size_t)rr * 128 + off) = v;
    }

    // attention projections (fp32, from accumulators)
    float as[8], ad[8];
    #pragma unroll
    for (int nt = 0; nt < 8; nt++) {
        as[nt] = a_src[nt * 16 + col];
        ad[nt] = a_dst[nt * 16 + col];
    }
    #pragma unroll
    for (int r = 0; r < 4; r++) {
        float ps[4], pd[4];
        #pragma unroll
        for (int hd = 0; hd < 4; hd++) {
            ps[hd] = acc[2 * hd][r] * as[2 * hd] + acc[2 * hd + 1][r] * as[2 * hd + 1];
            pd[hd] = acc[2 * hd][r] * ad[2 * hd] + acc[2 * hd + 1][r] * ad[2 * hd + 1];
            ps[hd] += __shfl_xor(ps[hd], 1); pd[hd] += __shfl_xor(pd[hd], 1);
            ps[hd] += __shfl_xor(ps[hd], 2); pd[hd] += __shfl_xor(pd[hd], 2);
            ps[hd] += __shfl_xor(ps[hd], 4); pd[hd] += __shfl_xor(pd[hd], 4);
            ps[hd] += __shfl_xor(ps[hd], 8); pd[hd] += __shfl_xor(pd[hd], 8);
        }
        int rr = row0 + w * 16 + quad * 4 + r;
        if (col == 0 && rr < NN) {
            *(float4*)(als + (size_t)rr * 4) = make_float4(ps[0], ps[1], ps[2], ps[3]);
            *(float4*)(ald + (size_t)rr * 4) = make_float4(pd[0], pd[1], pd[2], pd[3]);
        }
    }
}

// ---------------- per-node softmax aggregation (fp16 h gathers) ----------------
template <int FINAL>
__launch_bounds__(256)
__global__ void agg_kernel(const __half* __restrict__ h, const float* __restrict__ als_,
                           const float* __restrict__ ald_, const int* __restrict__ row_start,
                           const int* __restrict__ src_sorted, const float* __restrict__ bias,
                           float* __restrict__ outf, __half* __restrict__ outh) {
    __shared__ float lds_p[4][4][68];   // [wave][head][edge]
    __shared__ int   lds_s[4][64];
    int wid = threadIdx.x >> 6;
    int lane = threadIdx.x & 63;
    int node = blockIdx.x * 4 + wid;
    if (node >= NN) return;
    int sub  = lane >> 4;    // edge slot
    int cg   = lane & 15;    // channel group
    int c0   = cg * 8;
    int head = cg >> 2;

    int start = row_start[node], end = row_start[node + 1];
    float4 adv = *(const float4*)(ald_ + (size_t)node * 4);
    float4 avs = *(const float4*)(als_ + (size_t)node * 4);

    // self-loop (sub==0 only; sub-reduced at the end)
    float p_self = __expf(lrelu(sel4(avs, head) + sel4(adv, head)));
    float pinit = (sub == 0) ? p_self : 0.f;
    float s_sum = pinit;
    float acc[8];
    {
        float4 raw = *(const float4*)(h + (size_t)node * 128 + c0);
        const __half2* q2 = (const __half2*)&raw;
        #pragma unroll
        for (int i = 0; i < 4; i++) {
            float2 f = __half22float2(q2[i]);
            acc[2 * i] = f.x * pinit;
            acc[2 * i + 1] = f.y * pinit;
        }
    }

    for (int base = start; base < end; base += 64) {
        int j = base + lane;
        int my = 0;
        float4 p4 = make_float4(0.f, 0.f, 0.f, 0.f);
        if (j < end) {
            my = src_sorted[j];
            float4 av = *(const float4*)(als_ + (size_t)my * 4);
            p4.x = __expf(lrelu(av.x + adv.x));
            p4.y = __expf(lrelu(av.y + adv.y));
            p4.z = __expf(lrelu(av.z + adv.z));
            p4.w = __expf(lrelu(av.w + adv.w));
        }
        lds_s[wid][lane] = my;
        lds_p[wid][0][lane] = p4.x;
        lds_p[wid][1][lane] = p4.y;
        lds_p[wid][2][lane] = p4.z;
        lds_p[wid][3][lane] = p4.w;
        __builtin_amdgcn_wave_barrier();

        int cnt = end - base;
        if (cnt > 64) cnt = 64;
        for (int jj = 0; jj < cnt; jj += 16) {
            int   s[4];
            float p[4];
            #pragma unroll
            for (int i = 0; i < 4; i++) {
                int e = jj + 4 * i + sub;
                bool v = e < cnt;
                int ec = v ? e : 0;
                s[i] = lds_s[wid][ec];
                float pv = lds_p[wid][head][ec];
                p[i] = v ? pv : 0.f;
            }
            float4 raw[4];
            #pragma unroll
            for (int i = 0; i < 4; i++)
                raw[i] = *(const float4*)(h + (size_t)s[i] * 128 + c0);
            #pragma unroll
            for (int i = 0; i < 4; i++) {
                const __half2* q2 = (const __half2*)&raw[i];
                float2 f0 = __half22float2(q2[0]);
                float2 f1 = __half22float2(q2[1]);
                float2 f2 = __half22float2(q2[2]);
                float2 f3 = __half22float2(q2[3]);
                s_sum += p[i];
                acc[0] += f0.x * p[i]; acc[1] += f0.y * p[i];
                acc[2] += f1.x * p[i]; acc[3] += f1.y * p[i];
                acc[4] += f2.x * p[i]; acc[5] += f2.y * p[i];
                acc[6] += f3.x * p[i]; acc[7] += f3.y * p[i];
            }
        }
        __builtin_amdgcn_wave_barrier();
    }

    #pragma unroll
    for (int i = 0; i < 8; i++) {
        acc[i] += __shfl_xor(acc[i], 16);
        acc[i] += __shfl_xor(acc[i], 32);
    }
    s_sum += __shfl_xor(s_sum, 16);
    s_sum += __shfl_xor(s_sum, 32);

    float invs = 1.0f / (s_sum + 1e-16f);
    float t0 = (sub & 1) ? acc[2] : acc[0];
    float t1 = (sub & 1) ? acc[6] : acc[4];
    float num0 = (sub & 2) ? t1 : t0;
    float u0 = (sub & 1) ? acc[3] : acc[1];
    float u1 = (sub & 1) ? acc[7] : acc[5];
    float num1 = (sub & 2) ? u1 : u0;
    int cc = c0 + 2 * sub;
    float2 bv = *(const float2*)(bias + cc);
    float o0 = gelu_f(num0 * invs + bv.x);
    float o1 = gelu_f(num1 * invs + bv.y);
    if (FINAL) {
        *(float2*)(outf + (size_t)node * 128 + cc) = make_float2(o0, o1);
    } else {
        *(__half2*)(outh + (size_t)node * 128 + cc) = __floats2half2_rn(o0, o1);
    }
}

extern "C" void kernel_launch(void* const* d_in, const int* in_sizes, int n_in,
                              void* d_out, int out_size, void* d_ws, size_t ws_size,
                              hipStream_t stream) {
    const int*   label = (const int*)d_in[0];
    const int*   eidx  = (const int*)d_in[1];          // [2, NE]
    const float* rq    = (const float*)d_in[3];
    const float* emb   = (const float*)d_in[4];
    const float* reqW  = (const float*)d_in[5];
    const float* reqb  = (const float*)d_in[6];
    const float* W[3]    = {(const float*)d_in[7],  (const float*)d_in[11], (const float*)d_in[15]};
    const float* asrc[3] = {(const float*)d_in[8],  (const float*)d_in[12], (const float*)d_in[16]};
    const float* adst[3] = {(const float*)d_in[9],  (const float*)d_in[13], (const float*)d_in[17]};
    const float* bias[3] = {(const float*)d_in[10], (const float*)d_in[14], (const float*)d_in[18]};

    const int* e_src = eidx;
    const int* e_dst = eidx + NE;

    char* ws = (char*)d_ws;
    size_t off = 0;
    auto A = [&](size_t n) { size_t o = off; off += (n + 255) & ~(size_t)255; return o; };
    size_t o_bcnt  = A(256 * 4);               // zeroed
    size_t o_stats = A(8);                     // zeroed
    size_t zero_bytes = off;
    size_t o_bbase = A(257 * 4);
    size_t o_bcur  = A(256 * 4);
    size_t o_row   = A((size_t)(NN + 1) * 4);
    size_t o_etmp  = A((size_t)NE * 8);
    size_t o_srcS  = A((size_t)NE * 4);
    size_t o_x     = A((size_t)NN * 128 * 2);  // fp16
    size_t o_h     = A((size_t)NN * 128 * 2);  // fp16
    size_t o_als   = A((size_t)NN * 4 * 4);
    size_t o_ald   = A((size_t)NN * 4 * 4);
    (void)ws_size; (void)n_in; (void)in_sizes; (void)out_size;

    int*    bcnt   = (int*)(ws + o_bcnt);
    float*  stats  = (float*)(ws + o_stats);
    int*    bbase  = (int*)(ws + o_bbase);
    int*    bcur   = (int*)(ws + o_bcur);
    int*    rowst  = (int*)(ws + o_row);
    int2*   etmp   = (int2*)(ws + o_etmp);
    int*    srcS   = (int*)(ws + o_srcS);
    __half* xh     = (__half*)(ws + o_x);
    __half* h      = (__half*)(ws + o_h);
    float*  als    = (float*)(ws + o_als);
    float*  ald    = (float*)(ws + o_ald);

    (void)hipMemsetAsync(ws, 0, zero_bytes, stream);

    // frontend stats + bucket histogram
    stats_hist_kernel<<<STATS_BLOCKS + HIST_BLOCKS, 256, 0, stream>>>(rq, stats, e_dst, bcnt);
    bucket_scan_kernel<<<1, 256, 0, stream>>>(bcnt, bbase, bcur);
    binA_kernel<<<HIST_BLOCKS, 256, 0, stream>>>(e_src, e_dst, bcur, etmp);
    binB_kernel<<<NB, 256, 0, stream>>>(etmp, bbase, rowst, srcS);

    // 3 GAT layers
    const int gemm_blocks = (NN + 63) / 64;        // 782
    const int agg_blocks = (NN + 3) / 4;           // 12500
    for (int l = 0; l < 3; l++) {
        if (l == 0)
            gemm_al_kernel<1><<<gemm_blocks, 256, 0, stream>>>(xh, W[l], asrc[l], adst[l], h, als, ald,
                                                               label, rq, emb, reqW, reqb, stats);
        else
            gemm_al_kernel<0><<<gemm_blocks, 256, 0, stream>>>(xh, W[l], asrc[l], adst[l], h, als, ald,
                                                               label, rq, emb, reqW, reqb, stats);
        if (l == 2)
            agg_kernel<1><<<agg_blocks, 256, 0, stream>>>(h, als, ald, rowst, srcS, bias[l],
                                                          (float*)d_out, nullptr);
        else
            agg_kernel<0><<<agg_blocks, 256, 0, stream>>>(h, als, ald, rowst, srcS, bias[l],
                                                          nullptr, xh);
    }
}

// Round 9
// 292.079 us; speedup vs baseline: 1.7110x; 1.1073x over previous
//
#include <hip/hip_runtime.h>
#include <hip/hip_fp16.h>
#include <math.h>

#define NN 50000
#define NE 800000
#define HC 128
#define NHEAD 4
#define EMB 64
#define STATS_BLOCKS 64
#define NB 196           // buckets of 256 nodes
#define HIST_BLOCKS 196  // ceil(NE/4096)
#define WPREP_BLOCKS 192 // 3 layers x 64 blocks
#define WT_ROW 136       // padded fp16 W^T row (halves)

typedef _Float16 f16x8 __attribute__((ext_vector_type(8)));
typedef float f32x4 __attribute__((ext_vector_type(4)));

__device__ __forceinline__ float lrelu(float x) { return x > 0.0f ? x : 0.2f * x; }
__device__ __forceinline__ float gelu_f(float x) {
    return 0.5f * x * (1.0f + erff(x * 0.70710678118654752440f));
}
__device__ __forceinline__ float sel4(float4 v, int h) {
    float r = v.x;
    r = (h == 1) ? v.y : r;
    r = (h == 2) ? v.z : r;
    r = (h == 3) ? v.w : r;
    return r;
}
__device__ __forceinline__ f16x8 cvt8(float4 a, float4 b) {
    f16x8 v;
    v[0] = (_Float16)a.x; v[1] = (_Float16)a.y; v[2] = (_Float16)a.z; v[3] = (_Float16)a.w;
    v[4] = (_Float16)b.x; v[5] = (_Float16)b.y; v[6] = (_Float16)b.z; v[7] = (_Float16)b.w;
    return v;
}

// ---- fused frontend: stats | bucket histogram (dst>>8) | W->fp16 W^T prep ----
__global__ void prep_kernel(const float* __restrict__ rq, float* __restrict__ stats,
                            const int* __restrict__ dst, int* __restrict__ bucketCnt,
                            const float* __restrict__ W0, const float* __restrict__ W1,
                            const float* __restrict__ W2, _Float16* __restrict__ wt) {
    __shared__ float ls[4], ls2[4];
    __shared__ int cnt[NB];
    if (blockIdx.x < STATS_BLOCKS) {
        int i = blockIdx.x * 256 + threadIdx.x;
        float s = 0.f, s2 = 0.f;
        for (; i < NN; i += STATS_BLOCKS * 256) {
            float v = rq[i];
            s += v; s2 += v * v;
        }
        #pragma unroll
        for (int off = 32; off > 0; off >>= 1) {
            s  += __shfl_down(s, off);
            s2 += __shfl_down(s2, off);
        }
        int lane = threadIdx.x & 63, wid = threadIdx.x >> 6;
        if (lane == 0) { ls[wid] = s; ls2[wid] = s2; }
        __syncthreads();
        if (threadIdx.x == 0) {
            atomicAdd(&stats[0], ls[0] + ls[1] + ls[2] + ls[3]);
            atomicAdd(&stats[1], ls2[0] + ls2[1] + ls2[2] + ls2[3]);
        }
    } else if (blockIdx.x < STATS_BLOCKS + HIST_BLOCKS) {
        int bb = blockIdx.x - STATS_BLOCKS;
        for (int i = threadIdx.x; i < NB; i += 256) cnt[i] = 0;
        __syncthreads();
        int base = bb * 4096;
        #pragma unroll
        for (int it = 0; it < 16; it++) {
            int i = base + it * 256 + threadIdx.x;
            if (i < NE) atomicAdd(&cnt[dst[i] >> 8], 1);
        }
        __syncthreads();
        for (int i = threadIdx.x; i < NB; i += 256)
            if (cnt[i]) atomicAdd(&bucketCnt[i], cnt[i]);
    } else {
        int bb = blockIdx.x - STATS_BLOCKS - HIST_BLOCKS;   // 0..191
        int l = bb >> 6, blk = bb & 63;
        const float* W = (l == 0) ? W0 : (l == 1) ? W1 : W2;
        int idx = blk * 256 + threadIdx.x;   // 0..16383
        int n = idx >> 7, k = idx & 127;
        wt[(size_t)l * 128 * WT_ROW + n * WT_ROW + k] = (_Float16)W[k * 128 + n];
    }
}

// ---- in-block exclusive scan of bucketCnt; returns via LDS arrays ----
__device__ __forceinline__ void scan_buckets(const int* __restrict__ bucketCnt,
                                             int* sIncl /*LDS[256]*/) {
    int t = threadIdx.x;
    int v = (t < NB) ? bucketCnt[t] : 0;
    sIncl[t] = v;
    __syncthreads();
    #pragma unroll
    for (int off = 1; off < 256; off <<= 1) {
        int add = (t >= off) ? sIncl[t - off] : 0;
        __syncthreads();
        sIncl[t] += add;
        __syncthreads();
    }
}

// ------- binA: partition edges into bucket regions as (src, dst&255) pairs -------
__global__ void binA_kernel(const int* __restrict__ src, const int* __restrict__ dst,
                            const int* __restrict__ bucketCnt, int* __restrict__ gcur,
                            int2* __restrict__ edge_tmp) {
    __shared__ int sIncl[256];
    __shared__ int sBaseE[256];
    __shared__ int cnt[NB];
    __shared__ int cur[NB];
    int t = threadIdx.x;
    scan_buckets(bucketCnt, sIncl);
    {
        int v = (t < NB) ? bucketCnt[t] : 0;
        sBaseE[t] = sIncl[t] - v;
    }
    for (int i = t; i < NB; i += 256) cnt[i] = 0;
    __syncthreads();
    int base = blockIdx.x * 4096;
    int d[16], s[16];
    #pragma unroll
    for (int it = 0; it < 16; it++) {
        int i = base + it * 256 + t;
        bool ok = i < NE;
        d[it] = ok ? dst[i] : -1;
        s[it] = ok ? src[i] : 0;
        if (ok) atomicAdd(&cnt[d[it] >> 8], 1);
    }
    __syncthreads();
    for (int i = t; i < NB; i += 256)
        cur[i] = cnt[i] ? (sBaseE[i] + atomicAdd(&gcur[i], cnt[i])) : 0;
    __syncthreads();
    #pragma unroll
    for (int it = 0; it < 16; it++) {
        if (d[it] >= 0) {
            int b = d[it] >> 8;
            int pos = atomicAdd(&cur[b], 1);
            edge_tmp[pos] = make_int2(s[it], d[it] & 255);
        }
    }
}

// ------- binB: per-bucket local counting sort -> row_start + src_sorted -------
__global__ void binB_kernel(const int2* __restrict__ edge_tmp, const int* __restrict__ bucketCnt,
                            int* __restrict__ row_start, int* __restrict__ src_sorted) {
    __shared__ int sIncl[256];
    __shared__ int ldeg[256];
    __shared__ int lexcl[256];
    __shared__ int lcur[256];
    __shared__ int s_base, s_end;
    int b = blockIdx.x, t = threadIdx.x;
    scan_buckets(bucketCnt, sIncl);
    if (t == 0) {
        s_end = sIncl[b];
        s_base = sIncl[b] - bucketCnt[b];
    }
    ldeg[t] = 0;
    __syncthreads();
    int base = s_base, endb = s_end;
    for (int i = base + t; i < endb; i += 256)
        atomicAdd(&ldeg[edge_tmp[i].y], 1);
    __syncthreads();
    int v = ldeg[t];
    lexcl[t] = v;
    __syncthreads();
    #pragma unroll
    for (int off = 1; off < 256; off <<= 1) {
        int add = (t >= off) ? lexcl[t - off] : 0;
        __syncthreads();
        lexcl[t] += add;
        __syncthreads();
    }
    int excl = lexcl[t] - v;
    int node = b * 256 + t;
    if (node <= NN) row_start[node] = base + excl;
    lcur[t] = excl;
    __syncthreads();
    for (int i = base + t; i < endb; i += 256) {
        int2 e = edge_tmp[i];
        int pos = atomicAdd(&lcur[e.y], 1);
        src_sorted[base + pos] = e.x;
    }
}

// ---- fused MFMA GEMM + attention projections: h(fp16) = x@W ; als/ald fp32 ----
// 256 thr = 4 waves; tile M=64 (16/wave) x N=128 x K=128; v_mfma_f32_16x16x32_f16.
// W^T pre-converted fp16 [128][136] in global (wt). Dynamic LDS:
//   sWt [128*136]   (staged via linear b128 copy, conflict-free)
//   sX  [64*136]    (L0 only: on-the-fly x build; else A-frags direct from global)
// Epilogue reuses sWt region as transpose buffer (after __syncthreads).
template <int L0>
__launch_bounds__(256)
__global__ void gemm_al_kernel(const __half* __restrict__ xh, const _Float16* __restrict__ wt,
                               const float* __restrict__ a_src, const float* __restrict__ a_dst,
                               __half* __restrict__ h, float* __restrict__ als,
                               float* __restrict__ ald,
                               const int* __restrict__ label, const float* __restrict__ rq,
                               const float* __restrict__ emb, const float* __restrict__ reqW,
                               const float* __restrict__ reqb, const float* __restrict__ stats) {
    extern __shared__ char smem[];
    _Float16* sWt = (_Float16*)smem;            // [128][136]
    _Float16* sX  = sWt + 128 * WT_ROW;         // [64][136] (L0 only)
    int t = threadIdx.x;
    int w = t >> 6, l = t & 63;
    int col = l & 15, quad = l >> 4;
    int row0 = blockIdx.x * 64;

    // stage pre-converted W^T: linear b128 copy
    {
        const f16x8* g = (const f16x8*)wt;
        f16x8* s = (f16x8*)sWt;
        #pragma unroll
        for (int i = 0; i < 9; i++) {
            int idx = t + 256 * i;
            if (idx < 128 * WT_ROW / 8) s[idx] = g[idx];
        }
    }
    if (L0) {
        float sum = stats[0], sumsq = stats[1];
        float mean = sum / (float)NN;
        float var = (sumsq - sum * sum / (float)NN) / (float)(NN - 1);
        float inv = 1.0f / (sqrtf(var) + 1e-6f);
        #pragma unroll
        for (int i = 0; i < 4; i++) {
            int idx = t + 256 * i;   // 0..1023 8-half units
            int r = idx >> 4;        // 0..63
            int q = idx & 15;
            int rr = row0 + r;
            f16x8 v;
            #pragma unroll
            for (int j = 0; j < 8; j++) v[j] = (_Float16)0.f;
            if (rr < NN) {
                if (q < 8) {
                    const float4* er = (const float4*)(emb + (size_t)label[rr] * EMB);
                    v = cvt8(er[q * 2], er[q * 2 + 1]);
                } else {
                    int j4 = (q - 8) * 2;
                    float4 w0 = ((const float4*)reqW)[j4],     b0 = ((const float4*)reqb)[j4];
                    float4 w1 = ((const float4*)reqW)[j4 + 1], b1 = ((const float4*)reqb)[j4 + 1];
                    float r2 = (rq[rr] - mean) * inv;
                    v = cvt8(make_float4(r2 * w0.x + b0.x, r2 * w0.y + b0.y,
                                         r2 * w0.z + b0.z, r2 * w0.w + b0.w),
                             make_float4(r2 * w1.x + b1.x, r2 * w1.y + b1.y,
                                         r2 * w1.z + b1.z, r2 * w1.w + b1.w));
                }
            }
            *(f16x8*)&sX[r * WT_ROW + q * 8] = v;
        }
    }
    __syncthreads();

    // A-frags: wave-local row w*16+col
    f16x8 afr[4];
    if (L0) {
        #pragma unroll
        for (int ks = 0; ks < 4; ks++)
            afr[ks] = *(const f16x8*)&sX[(w * 16 + col) * WT_ROW + ks * 32 + quad * 8];
    } else {
        int rr = row0 + w * 16 + col;               // OOB reads land in d_ws (safe, masked later)
        const __half* xp = xh + (size_t)rr * 128;
        #pragma unroll
        for (int ks = 0; ks < 4; ks++)
            afr[ks] = *(const f16x8*)(xp + ks * 32 + quad * 8);
    }

    f32x4 zero = {0.f, 0.f, 0.f, 0.f};
    f32x4 acc[8];
    #pragma unroll
    for (int nt = 0; nt < 8; nt++) acc[nt] = zero;
    #pragma unroll
    for (int nt = 0; nt < 8; nt++) {
        #pragma unroll
        for (int ks = 0; ks < 4; ks++) {
            f16x8 bfr = *(const f16x8*)&sWt[(nt * 16 + col) * WT_ROW + ks * 32 + quad * 8];
            acc[nt] = __builtin_amdgcn_mfma_f32_16x16x32_f16(afr[ks], bfr, acc[nt], 0, 0, 0);
        }
    }
    __syncthreads();   // all MFMA reads of sWt done; reuse as transpose buffer

    // h store: transpose via LDS (wave-own rows), then coalesced b128 stores
    _Float16* sOut = sWt;   // [64][136]
    #pragma unroll
    for (int nt = 0; nt < 8; nt++)
        #pragma unroll
        for (int r = 0; r < 4; r++)
            sOut[(w * 16 + quad * 4 + r) * WT_ROW + nt * 16 + col] = (_Float16)acc[nt][r];
    __builtin_amdgcn_wave_barrier();
    #pragma unroll
    for (int i = 0; i < 4; i++) {
        int u = l + 64 * i;          // 0..255
        int r = u >> 4, off = (u & 15) * 8;
        int rr = row0 + w * 16 + r;
        f16x8 v = *(const f16x8*)&sOut[(w * 16 + r) * WT_ROW + off];
        if (rr < NN) *(f16x8*)(h + (size_t)rr * 128 + off) = v;
    }

    // attention projections (fp32, from accumulators)
    float as[8], ad[8];
    #pragma unroll
    for (int nt = 0; nt < 8; nt++) {
        as[nt] = a_src[nt * 16 + col];
        ad[nt] = a_dst[nt * 16 + col];
    }
    #pragma unroll
    for (int r = 0; r < 4; r++) {
        float ps[4], pd[4];
        #pragma unroll
        for (int hd = 0; hd < 4; hd++) {
            ps[hd] = acc[2 * hd][r] * as[2 * hd] + acc[2 * hd + 1][r] * as[2 * hd + 1];
            pd[hd] = acc[2 * hd][r] * ad[2 * hd] + acc[2 * hd + 1][r] * ad[2 * hd + 1];
            ps[hd] += __shfl_xor(ps[hd], 1); pd[hd] += __shfl_xor(pd[hd], 1);
            ps[hd] += __shfl_xor(ps[hd], 2); pd[hd] += __shfl_xor(pd[hd], 2);
            ps[hd] += __shfl_xor(ps[hd], 4); pd[hd] += __shfl_xor(pd[hd], 4);
            ps[hd] += __shfl_xor(ps[hd], 8); pd[hd] += __shfl_xor(pd[hd], 8);
        }
        int rr = row0 + w * 16 + quad * 4 + r;
        if (col == 0 && rr < NN) {
            *(float4*)(als + (size_t)rr * 4) = make_float4(ps[0], ps[1], ps[2], ps[3]);
            *(float4*)(ald + (size_t)rr * 4) = make_float4(pd[0], pd[1], pd[2], pd[3]);
        }
    }
}

// ---------------- per-node softmax aggregation (fp16 h gathers) ----------------
template <int FINAL>
__launch_bounds__(256)
__global__ void agg_kernel(const __half* __restrict__ h, const float* __restrict__ als_,
                           const float* __restrict__ ald_, const int* __restrict__ row_start,
                           const int* __restrict__ src_sorted, const float* __restrict__ bias,
                           float* __restrict__ outf, __half* __restrict__ outh) {
    __shared__ float lds_p[4][4][68];   // [wave][head][edge]
    __shared__ int   lds_s[4][64];
    int wid = threadIdx.x >> 6;
    int lane = threadIdx.x & 63;
    int node = blockIdx.x * 4 + wid;
    if (node >= NN) return;
    int sub  = lane >> 4;    // edge slot
    int cg   = lane & 15;    // channel group
    int c0   = cg * 8;
    int head = cg >> 2;

    int start = row_start[node], end = row_start[node + 1];
    float4 adv = *(const float4*)(ald_ + (size_t)node * 4);
    float4 avs = *(const float4*)(als_ + (size_t)node * 4);

    // self-loop (sub==0 only; sub-reduced at the end)
    float p_self = __expf(lrelu(sel4(avs, head) + sel4(adv, head)));
    float pinit = (sub == 0) ? p_self : 0.f;
    float s_sum = pinit;
    float acc[8];
    {
        float4 raw = *(const float4*)(h + (size_t)node * 128 + c0);
        const __half2* q2 = (const __half2*)&raw;
        #pragma unroll
        for (int i = 0; i < 4; i++) {
            float2 f = __half22float2(q2[i]);
            acc[2 * i] = f.x * pinit;
            acc[2 * i + 1] = f.y * pinit;
        }
    }

    for (int base = start; base < end; base += 64) {
        int j = base + lane;
        int my = 0;
        float4 p4 = make_float4(0.f, 0.f, 0.f, 0.f);
        if (j < end) {
            my = src_sorted[j];
            float4 av = *(const float4*)(als_ + (size_t)my * 4);
            p4.x = __expf(lrelu(av.x + adv.x));
            p4.y = __expf(lrelu(av.y + adv.y));
            p4.z = __expf(lrelu(av.z + adv.z));
            p4.w = __expf(lrelu(av.w + adv.w));
        }
        lds_s[wid][lane] = my;
        lds_p[wid][0][lane] = p4.x;
        lds_p[wid][1][lane] = p4.y;
        lds_p[wid][2][lane] = p4.z;
        lds_p[wid][3][lane] = p4.w;
        __builtin_amdgcn_wave_barrier();

        int cnt = end - base;
        if (cnt > 64) cnt = 64;
        for (int jj = 0; jj < cnt; jj += 16) {
            int   s[4];
            float p[4];
            #pragma unroll
            for (int i = 0; i < 4; i++) {
                int e = jj + 4 * i + sub;
                bool v = e < cnt;
                int ec = v ? e : 0;
                s[i] = lds_s[wid][ec];
                float pv = lds_p[wid][head][ec];
                p[i] = v ? pv : 0.f;
            }
            float4 raw[4];
            #pragma unroll
            for (int i = 0; i < 4; i++)
                raw[i] = *(const float4*)(h + (size_t)s[i] * 128 + c0);
            #pragma unroll
            for (int i = 0; i < 4; i++) {
                const __half2* q2 = (const __half2*)&raw[i];
                float2 f0 = __half22float2(q2[0]);
                float2 f1 = __half22float2(q2[1]);
                float2 f2 = __half22float2(q2[2]);
                float2 f3 = __half22float2(q2[3]);
                s_sum += p[i];
                acc[0] += f0.x * p[i]; acc[1] += f0.y * p[i];
                acc[2] += f1.x * p[i]; acc[3] += f1.y * p[i];
                acc[4] += f2.x * p[i]; acc[5] += f2.y * p[i];
                acc[6] += f3.x * p[i]; acc[7] += f3.y * p[i];
            }
        }
        __builtin_amdgcn_wave_barrier();
    }

    #pragma unroll
    for (int i = 0; i < 8; i++) {
        acc[i] += __shfl_xor(acc[i], 16);
        acc[i] += __shfl_xor(acc[i], 32);
    }
    s_sum += __shfl_xor(s_sum, 16);
    s_sum += __shfl_xor(s_sum, 32);

    float invs = 1.0f / (s_sum + 1e-16f);
    float t0 = (sub & 1) ? acc[2] : acc[0];
    float t1 = (sub & 1) ? acc[6] : acc[4];
    float num0 = (sub & 2) ? t1 : t0;
    float u0 = (sub & 1) ? acc[3] : acc[1];
    float u1 = (sub & 1) ? acc[7] : acc[5];
    float num1 = (sub & 2) ? u1 : u0;
    int cc = c0 + 2 * sub;
    float2 bv = *(const float2*)(bias + cc);
    float o0 = gelu_f(num0 * invs + bv.x);
    float o1 = gelu_f(num1 * invs + bv.y);
    if (FINAL) {
        *(float2*)(outf + (size_t)node * 128 + cc) = make_float2(o0, o1);
    } else {
        *(__half2*)(outh + (size_t)node * 128 + cc) = __floats2half2_rn(o0, o1);
    }
}

extern "C" void kernel_launch(void* const* d_in, const int* in_sizes, int n_in,
                              void* d_out, int out_size, void* d_ws, size_t ws_size,
                              hipStream_t stream) {
    const int*   label = (const int*)d_in[0];
    const int*   eidx  = (const int*)d_in[1];          // [2, NE]
    const float* rq    = (const float*)d_in[3];
    const float* emb   = (const float*)d_in[4];
    const float* reqW  = (const float*)d_in[5];
    const float* reqb  = (const float*)d_in[6];
    const float* W[3]    = {(const float*)d_in[7],  (const float*)d_in[11], (const float*)d_in[15]};
    const float* asrc[3] = {(const float*)d_in[8],  (const float*)d_in[12], (const float*)d_in[16]};
    const float* adst[3] = {(const float*)d_in[9],  (const float*)d_in[13], (const float*)d_in[17]};
    const float* bias[3] = {(const float*)d_in[10], (const float*)d_in[14], (const float*)d_in[18]};

    const int* e_src = eidx;
    const int* e_dst = eidx + NE;

    char* ws = (char*)d_ws;
    size_t off = 0;
    auto A = [&](size_t n) { size_t o = off; off += (n + 255) & ~(size_t)255; return o; };
    size_t o_bcnt  = A(256 * 4);               // zeroed
    size_t o_gcur  = A(256 * 4);               // zeroed
    size_t o_stats = A(8);                     // zeroed
    size_t zero_bytes = off;
    size_t o_row   = A((size_t)(NN + 1) * 4);
    size_t o_etmp  = A((size_t)NE * 8);
    size_t o_srcS  = A((size_t)NE * 4);
    size_t o_wt    = A((size_t)3 * 128 * WT_ROW * 2);
    size_t o_x     = A((size_t)NN * 128 * 2);  // fp16
    size_t o_h     = A((size_t)NN * 128 * 2);  // fp16
    size_t o_als   = A((size_t)NN * 4 * 4);
    size_t o_ald   = A((size_t)NN * 4 * 4);
    (void)ws_size; (void)n_in; (void)in_sizes; (void)out_size;

    int*      bcnt  = (int*)(ws + o_bcnt);
    int*      gcur  = (int*)(ws + o_gcur);
    float*    stats = (float*)(ws + o_stats);
    int*      rowst = (int*)(ws + o_row);
    int2*     etmp  = (int2*)(ws + o_etmp);
    int*      srcS  = (int*)(ws + o_srcS);
    _Float16* wt    = (_Float16*)(ws + o_wt);
    __half*   xh    = (__half*)(ws + o_x);
    __half*   h     = (__half*)(ws + o_h);
    float*    als   = (float*)(ws + o_als);
    float*    ald   = (float*)(ws + o_ald);

    (void)hipMemsetAsync(ws, 0, zero_bytes, stream);

    // fused: stats | bucket histogram | W^T fp16 prep
    prep_kernel<<<STATS_BLOCKS + HIST_BLOCKS + WPREP_BLOCKS, 256, 0, stream>>>(
        rq, stats, e_dst, bcnt, W[0], W[1], W[2], wt);
    binA_kernel<<<HIST_BLOCKS, 256, 0, stream>>>(e_src, e_dst, bcnt, gcur, etmp);
    binB_kernel<<<NB, 256, 0, stream>>>(etmp, bcnt, rowst, srcS);

    // 3 GAT layers
    const int gemm_blocks = (NN + 63) / 64;        // 782
    const int agg_blocks = (NN + 3) / 4;           // 12500
    const int smem_l0 = (128 + 64) * WT_ROW * 2;   // 52224 B
    const int smem_ln = 128 * WT_ROW * 2;          // 34816 B
    for (int l = 0; l < 3; l++) {
        const _Float16* wtl = wt + (size_t)l * 128 * WT_ROW;
        if (l == 0)
            gemm_al_kernel<1><<<gemm_blocks, 256, smem_l0, stream>>>(
                xh, wtl, asrc[l], adst[l], h, als, ald, label, rq, emb, reqW, reqb, stats);
        else
            gemm_al_kernel<0><<<gemm_blocks, 256, smem_ln, stream>>>(
                xh, wtl, asrc[l], adst[l], h, als, ald, label, rq, emb, reqW, reqb, stats);
        if (l == 2)
            agg_kernel<1><<<agg_blocks, 256, 0, stream>>>(h, als, ald, rowst, srcS, bias[l],
                                                          (float*)d_out, nullptr);
        else
            agg_kernel<0><<<agg_blocks, 256, 0, stream>>>(h, als, ald, rowst, srcS, bias[l],
                                                          nullptr, xh);
    }
}